// Round 13
// baseline (2078.512 us; speedup 1.0000x reference)
//
#include <hip/hip_runtime.h>
#include <math.h>

// Problem dims
#define S_N   512
#define WL_N  100
#define E_N   200
#define OC_N  50
#define H_N   400

// ---------------------------------------------------------------------------
// K1a: window_kernel — Awin[s][dd*200+e] = (1/L)*sum_{t<L} in[e][t+(dd-7)]
// ---------------------------------------------------------------------------
__global__ __launch_bounds__(256, 1)
void window_kernel(const int* __restrict__ x, const float* __restrict__ emb,
                   float* __restrict__ Awin, int stride)
{
  const int s = blockIdx.x;
  const int tid = threadIdx.x;
  __shared__ int xr[WL_N];
  __shared__ int Lsh;
  __shared__ float Apart[E_N][17];
  __shared__ float Bpart[E_N][9];
  if (tid < WL_N) xr[tid] = x[s * WL_N + tid];
  for (int idx = tid; idx < stride - 3000; idx += 256)
    Awin[(size_t)s * stride + 3000 + idx] = 0.f;
  __syncthreads();
  if (tid == 0) {
    int L = 0;
    for (int t = 0; t < WL_N; ++t) L += (xr[t] != 0) ? 1 : 0;
    Lsh = L;
  }
  __syncthreads();
  const int L = Lsh;  // in [20,100]
  const int Lp7 = (L + 7 < WL_N) ? (L + 7) : WL_N;
  if (tid < E_N) {
    const int e = tid;
    float acc = 0.f;
    for (int t = 0; t < Lp7; ++t) {
      acc += emb[(size_t)xr[t] * E_N + e];
      int m = t + 1;
      if (m <= 7) Bpart[e][m] = acc;
      int rel = m - (L - 7);
      if (rel >= 0 && rel < 15) Apart[e][rel] = acc;
    }
    const float accF = acc;
    const float invL = 1.f / (float)L;
    #pragma unroll
    for (int dd = 0; dd < 15; ++dd) {
      int m = L - 7 + dd;
      float A = (m > WL_N) ? accF : Apart[e][dd];
      int d = dd - 7;
      float B = (d > 0) ? Bpart[e][d] : 0.f;
      Awin[(size_t)s * stride + dd * 200 + e] = (A - B) * invL;
    }
  }
}

// ---------------------------------------------------------------------------
// K1b-fast: pad_kernel — Wpad[400][3072] materialized padded conv weights
// ---------------------------------------------------------------------------
__global__ __launch_bounds__(256, 4)
void pad_kernel(const float* __restrict__ cw0, const float* __restrict__ cw1,
                const float* __restrict__ cw2, const float* __restrict__ cw3,
                const float* __restrict__ cw4, const float* __restrict__ cw5,
                const float* __restrict__ cw6, const float* __restrict__ cw7,
                float* __restrict__ Wpad)
{
  const int gcol = blockIdx.x;
  const int tid = threadIdx.x;
  const float* cwA[8] = {cw0, cw1, cw2, cw3, cw4, cw5, cw6, cw7};
  const int K = gcol / 50, oc = gcol % 50;
  const int width = 2 * K + 1;
  const int lo = 7 - K;
  const float* base = cwA[K] + (size_t)oc * 200 * width;
  for (int k = tid; k < 3072; k += 256) {
    float v = 0.f;
    if (k < 3000) {
      int dd = k / 200, e = k - dd * 200;
      int off = dd - lo;
      if (off >= 0 && off < width) v = base[e * width + off];
    }
    Wpad[(size_t)gcol * 3072 + k] = v;
  }
}

// ---------------------------------------------------------------------------
// K1b-fallback: gemm_pool on-the-fly (r10-proven; used only if ws too small)
// ---------------------------------------------------------------------------
__global__ __launch_bounds__(256, 2)
void gemm_pool(const float* __restrict__ Awin,
               const float* __restrict__ cw0, const float* __restrict__ cw1,
               const float* __restrict__ cw2, const float* __restrict__ cw3,
               const float* __restrict__ cw4, const float* __restrict__ cw5,
               const float* __restrict__ cw6, const float* __restrict__ cw7,
               const float* __restrict__ conv_b,
               float* __restrict__ pooled)
{
  __shared__ float As[16][65];
  __shared__ float Bs[16][65];
  const int bm = blockIdx.y * 64, bn = blockIdx.x * 64;
  const int tid = threadIdx.x;
  const int tr = (tid / 16) * 4, tc = (tid % 16) * 4;
  const int c = tid & 15;

  const float* cwA[8] = {cw0, cw1, cw2, cw3, cw4, cw5, cw6, cw7};
  const float* base_i[4];
  int lo_i[4], w_i[4];
  bool valid_i[4];
  #pragma unroll
  for (int i = 0; i < 4; ++i) {
    int gcol = bn + (tid >> 4) + 16 * i;
    bool v = (gcol < 400);
    int g = v ? gcol : 0;
    int K = g / 50, oc = g % 50;
    int width = 2 * K + 1;
    valid_i[i] = v;
    lo_i[i] = 7 - K;
    w_i[i] = width;
    base_i[i] = cwA[K] + (size_t)oc * 200 * width;
  }

  float acc[4][4] = {};
  int e = c, dd = 0;
  for (int k0 = 0; k0 < 3000; k0 += 16) {
    for (int l = tid; l < 64 * 16; l += 256) {
      int r = l >> 4, cc2 = l & 15;
      int k = k0 + cc2;
      As[cc2][r] = (k < 3000) ? Awin[(size_t)(bm + r) * 3000 + k] : 0.f;
    }
    #pragma unroll
    for (int i = 0; i < 4; ++i) {
      int r = (tid >> 4) + 16 * i;
      int off = dd - lo_i[i];
      float v = 0.f;
      if (valid_i[i] && off >= 0 && off < w_i[i])
        v = base_i[i][e * w_i[i] + off];
      Bs[c][r] = v;
    }
    __syncthreads();
    #pragma unroll
    for (int kk = 0; kk < 16; ++kk) {
      float a[4], b[4];
      #pragma unroll
      for (int u = 0; u < 4; ++u) { a[u] = As[kk][tr + u]; b[u] = Bs[kk][tc + u]; }
      #pragma unroll
      for (int u = 0; u < 4; ++u)
        #pragma unroll
        for (int v = 0; v < 4; ++v) acc[u][v] += a[u] * b[v];
    }
    __syncthreads();
    e += 16;
    if (e >= 200) { e -= 200; dd += 1; }
  }
  for (int u = 0; u < 4; ++u) {
    int r = bm + tr + u;
    for (int v = 0; v < 4; ++v) {
      int cc2 = bn + tc + v; if (cc2 >= 400) continue;
      pooled[(size_t)r * 400 + cc2] = acc[u][v] + conv_b[cc2];
    }
  }
}

// ---------------------------------------------------------------------------
// K2: gemm_gi (+ zero hbuf AND fastbuf+ctl in block (0,0))
// ---------------------------------------------------------------------------
__global__ __launch_bounds__(256, 2)
void gemm_gi(const float* __restrict__ A,
             const float* __restrict__ wf, const float* __restrict__ bf,
             const float* __restrict__ wb, const float* __restrict__ bb,
             float* __restrict__ C,
             unsigned long long* __restrict__ hz,
             unsigned long long* __restrict__ fz)
{
  __shared__ float As[16][65];
  __shared__ float Bs[16][65];
  const int bm = blockIdx.y * 64, bn = blockIdx.x * 64;
  const int tid = threadIdx.x;
  const int tr = (tid / 16) * 4, tc = (tid % 16) * 4;
  if (blockIdx.x == 0 && blockIdx.y == 0) {
    for (int l = tid; l < 1600; l += 256) hz[l] = 0ull;
    for (int l = tid; l < 1608; l += 256) fz[l] = 0ull;  // fastbuf + ctl
  }
  float acc[4][4] = {};
  for (int k0 = 0; k0 < 400; k0 += 16) {
    for (int l = tid; l < 64 * 16; l += 256) {
      int r = l / 16, c = l % 16;
      As[c][r] = A[(size_t)(bm + r) * 400 + k0 + c];
    }
    for (int l = tid; l < 64 * 16; l += 256) {
      int r = l / 16, c = l % 16;
      int gcol = bn + r;
      float v = 0.f;
      if (gcol < 1200)      v = wf[(size_t)gcol * 400 + k0 + c];
      else if (gcol < 2400) v = wb[(size_t)(gcol - 1200) * 400 + k0 + c];
      Bs[c][r] = v;
    }
    __syncthreads();
    #pragma unroll
    for (int kk = 0; kk < 16; ++kk) {
      float a[4], b[4];
      #pragma unroll
      for (int u = 0; u < 4; ++u) { a[u] = As[kk][tr + u]; b[u] = Bs[kk][tc + u]; }
      #pragma unroll
      for (int u = 0; u < 4; ++u)
        #pragma unroll
        for (int v = 0; v < 4; ++v) acc[u][v] += a[u] * b[v];
    }
    __syncthreads();
  }
  for (int u = 0; u < 4; ++u) {
    int r = bm + tr + u;
    for (int v = 0; v < 4; ++v) {
      int c = bn + tc + v; if (c >= 2400) continue;
      float bias = (c < 1200) ? bf[c] : bb[c - 1200];
      C[(size_t)r * 2400 + c] = acc[u][v] + bias;
    }
  }
}

// ---------------------------------------------------------------------------
// 32x32-tile GEMM: C = A@B^T + bias (optional tanh)
// ---------------------------------------------------------------------------
template<int TAG>
__global__ __launch_bounds__(256, 4)
void gemm32(const float* __restrict__ A, int lda,
            const float* __restrict__ Bw, int ldb,
            const float* __restrict__ bias,
            float* __restrict__ C, int ldc,
            int M, int N, int K, int act)
{
  __shared__ float As[32][33];
  __shared__ float Bs[32][33];
  const int bm = blockIdx.y * 32, bn = blockIdx.x * 32;
  const int tid = threadIdx.x;
  const int tr = (tid >> 4) * 2, tc = (tid & 15) * 2;
  float acc[2][2] = {};
  for (int k0 = 0; k0 < K; k0 += 32) {
    #pragma unroll
    for (int p = 0; p < 4; ++p) {
      int l = tid + p * 256;
      int r = l >> 5, c = l & 31;
      As[c][r] = (bm + r < M) ? A[(size_t)(bm + r) * lda + k0 + c] : 0.f;
      Bs[c][r] = (bn + r < N) ? Bw[(size_t)(bn + r) * ldb + k0 + c] : 0.f;
    }
    __syncthreads();
    #pragma unroll
    for (int kk = 0; kk < 32; ++kk) {
      float a0 = As[kk][tr], a1 = As[kk][tr + 1];
      float b0 = Bs[kk][tc], b1 = Bs[kk][tc + 1];
      acc[0][0] += a0 * b0; acc[0][1] += a0 * b1;
      acc[1][0] += a1 * b0; acc[1][1] += a1 * b1;
    }
    __syncthreads();
  }
  #pragma unroll
  for (int u = 0; u < 2; ++u) {
    int r = bm + tr + u; if (r >= M) continue;
    #pragma unroll
    for (int v = 0; v < 2; ++v) {
      int c = bn + tc + v; if (c >= N) continue;
      float xv = acc[u][v] + (bias ? bias[c] : 0.f);
      if (act == 1) xv = tanhf(xv);
      C[(size_t)r * ldc + c] = xv;
    }
  }
}

// ---------------------------------------------------------------------------
// K3: bidirectional GRU scan — r12 role-split protocol + XCD co-location.
// Placement: ticket-claim (target XCD via CAS of XCC_ID; blocks >=768 claim
// unconditionally -> ticket fill guaranteed; non-claimers exit).
// Transport: DUAL publish each step: fast u64 (plain store -> local L2) +
// slow u64 (agent atomic -> LLC, r12-proven). Probe at t==1 picks per-block
// mode: FAST (sc0 L2 polls; slow-guard every 64 spins) or SLOW (exact r12).
// Split placement can never confirm fast tags -> auto-SLOW. Correctness never
// depends on placement or sc0 semantics.
// ---------------------------------------------------------------------------
#define GRU_NB 25
#define GRU_CHUNK 16
#define GRU_NT 50
#define LDA64(p) __hip_atomic_load((p), __ATOMIC_RELAXED, __HIP_MEMORY_SCOPE_AGENT)
#define LO32F(x) __uint_as_float((unsigned)(x))

__global__ __launch_bounds__(256, 1)
void gru_scan_kernel(const float* __restrict__ gi,
                     const float* __restrict__ whh_f, const float* __restrict__ bhh_f,
                     const float* __restrict__ whh_b, const float* __restrict__ bhh_b,
                     float* __restrict__ enc,
                     float* __restrict__ mean,
                     unsigned long long* __restrict__ hbuf,   // slow [2][2][400]
                     unsigned long long* __restrict__ fbuf,   // fast [2][2][400]
                     unsigned int* __restrict__ ctl)          // [0]=target+1, [1]=tickets
{
  const int tid = threadIdx.x;
  __shared__ int tk_s;
  if (tid == 0) {
    unsigned xcc;
    asm volatile("s_getreg_b32 %0, hwreg(20, 0, 32)" : "=s"(xcc));
    xcc = (xcc & 0xFu) + 1u;
    unsigned tgt = __hip_atomic_load(&ctl[0], __ATOMIC_RELAXED, __HIP_MEMORY_SCOPE_AGENT);
    if (tgt == 0u) {
      unsigned old = atomicCAS(&ctl[0], 0u, xcc);
      tgt = (old == 0u) ? xcc : old;
    }
    int tk = -1;
    if (tgt == xcc || blockIdx.x >= 768) {
      unsigned cur = __hip_atomic_load(&ctl[1], __ATOMIC_RELAXED, __HIP_MEMORY_SCOPE_AGENT);
      if (cur < (unsigned)GRU_NT) {
        unsigned got = atomicAdd(&ctl[1], 1u);
        if (got < (unsigned)GRU_NT) tk = (int)got;
      }
    }
    tk_s = tk;
  }
  __syncthreads();
  const int tk = tk_s;
  if (tk < 0) return;
  const int dir = tk / GRU_NB;
  const int b   = tk - dir * GRU_NB;

  const float* whh = dir ? whh_b : whh_f;
  const float* bhh = dir ? bhh_b : bhh_f;
  unsigned long long* hb = hbuf + (size_t)dir * 800;
  unsigned long long* fb = fbuf + (size_t)dir * 800;
  const int i0 = b * GRU_CHUNK;

  __shared__ float wl[48][400];
  __shared__ float hs[400];
  __shared__ float ghs[48];
  volatile __shared__ int wflag[2];
  volatile __shared__ int s3step;
  volatile __shared__ int mode_s;

  for (int l = tid; l < 48 * 400; l += 256) {
    int lr = l / 400, c = l % 400;
    int g = lr / GRU_CHUNK, ii = lr % GRU_CHUNK;
    wl[lr][c] = whh[(size_t)(g * 400 + i0 + ii) * 400 + c];
  }

  const int i  = tid >> 4;
  const int cc = tid & 15;
  const int c0 = cc * 25;

  float blr = 0.f, blz = 0.f, bln = 0.f, msum = 0.f;
  float g0r = 0.f, g0z = 0.f, g0n = 0.f;
  float g1r = 0.f, g1z = 0.f, g1n = 0.f;
  if (tid < GRU_CHUNK) {
    blr = bhh[i0 + tid];
    blz = bhh[400 + i0 + tid];
    bln = bhh[800 + i0 + tid];
    {
      int t0 = dir ? 511 : 0;
      const float* g = gi + (size_t)t0 * 2400 + dir * 1200 + i0 + tid;
      g0r = g[0]; g0z = g[400]; g0n = g[800];
      int t1 = dir ? 510 : 1;
      g = gi + (size_t)t1 * 2400 + dir * 1200 + i0 + tid;
      g1r = g[0]; g1z = g[400]; g1n = g[800];
    }
  }
  if (tid == 0) { wflag[0] = -1; wflag[1] = -1; s3step = -1; mode_s = 0; }
  __syncthreads();

  for (int t = 0; t < 512; ++t) {
    const int t_in = dir ? (511 - t) : t;
    if (tid >= 64) {
      const unsigned want = (unsigned)t;
      const unsigned long long* fsrc = fb + (t & 1) * 400;
      const unsigned long long* ssrc = hb + (t & 1) * 400;
      const int mode = mode_s;
      if (mode == 1) {
        if (tid < 192) {
          // FAST steady: waves 1-2 poll local L2 (sc0), slow-guard every 64
          const int p2 = tid - 64;
          const bool f4 = (p2 < 16);
          const unsigned long long *q0 = fsrc + p2, *q1 = fsrc + p2 + 128,
                                   *q2 = fsrc + p2 + 256,
                                   *q3 = fsrc + (f4 ? p2 + 384 : p2);
          unsigned long long f0, f1, f2, f3;
          int spins = 0;
          for (;;) {
            asm volatile(
              "global_load_dwordx2 %0, %4, off sc0\n\t"
              "global_load_dwordx2 %1, %5, off sc0\n\t"
              "global_load_dwordx2 %2, %6, off sc0\n\t"
              "global_load_dwordx2 %3, %7, off sc0\n\t"
              "s_waitcnt vmcnt(0)"
              : "=&v"(f0), "=&v"(f1), "=&v"(f2), "=&v"(f3)
              : "v"(q0), "v"(q1), "v"(q2), "v"(q3)
              : "memory");
            bool ok = ((unsigned)(f0 >> 32) == want) && ((unsigned)(f1 >> 32) == want) &&
                      ((unsigned)(f2 >> 32) == want) && ((unsigned)(f3 >> 32) == want);
            if (__all(ok)) break;
            if (((++spins) & 63) == 0) {
              unsigned long long s0 = LDA64(ssrc + p2), s1 = LDA64(ssrc + p2 + 128),
                                 s2 = LDA64(ssrc + p2 + 256),
                                 s3v = f4 ? LDA64(ssrc + p2 + 384) : s0;
              ok = ((unsigned)(s0 >> 32) == want) && ((unsigned)(s1 >> 32) == want) &&
                   ((unsigned)(s2 >> 32) == want) && ((unsigned)(s3v >> 32) == want);
              if (__all(ok)) { f0 = s0; f1 = s1; f2 = s2; f3 = s3v; break; }
            }
          }
          hs[p2] = LO32F(f0); hs[p2 + 128] = LO32F(f1); hs[p2 + 256] = LO32F(f2);
          if (f4) hs[p2 + 384] = LO32F(f3);
          if ((tid & 63) == 0) wflag[(tid >> 6) - 1] = t;
        } else {
          while (wflag[0] < t || wflag[1] < t) __builtin_amdgcn_s_sleep(1);
        }
      } else if (mode == 2) {
        // SLOW steady: exact r12 2-deep pipelined LLC poll, waves 1-3
        const int p = tid - 64;
        const bool h2 = (p < 16);
        unsigned long long a0, a1, a2 = 0, b0, b1, b2 = 0, r0, r1, r2 = 0;
        a0 = LDA64(ssrc + p); a1 = LDA64(ssrc + p + 192); if (h2) a2 = LDA64(ssrc + p + 384);
        b0 = LDA64(ssrc + p); b1 = LDA64(ssrc + p + 192); if (h2) b2 = LDA64(ssrc + p + 384);
        for (;;) {
          bool ok = ((unsigned)(a0 >> 32) == want) && ((unsigned)(a1 >> 32) == want)
                    && (!h2 || ((unsigned)(a2 >> 32) == want));
          if (__all(ok)) { r0 = a0; r1 = a1; r2 = a2; break; }
          a0 = LDA64(ssrc + p); a1 = LDA64(ssrc + p + 192); if (h2) a2 = LDA64(ssrc + p + 384);
          ok = ((unsigned)(b0 >> 32) == want) && ((unsigned)(b1 >> 32) == want)
               && (!h2 || ((unsigned)(b2 >> 32) == want));
          if (__all(ok)) { r0 = b0; r1 = b1; r2 = b2; break; }
          b0 = LDA64(ssrc + p); b1 = LDA64(ssrc + p + 192); if (h2) b2 = LDA64(ssrc + p + 384);
        }
        hs[p] = LO32F(r0);
        hs[p + 192] = LO32F(r1);
        if (h2) hs[p + 384] = LO32F(r2);
      } else {
        // UNDECIDED (t <= 1): fast vs slow race; wave 3 votes at t==1
        if (tid < 192) {
          const int p2 = tid - 64;
          const bool f4 = (p2 < 16);
          const unsigned long long *q0 = fsrc + p2, *q1 = fsrc + p2 + 128,
                                   *q2 = fsrc + p2 + 256,
                                   *q3 = fsrc + (f4 ? p2 + 384 : p2);
          unsigned long long f0, f1, f2, f3;
          bool got = false;
          for (;;) {
            asm volatile(
              "global_load_dwordx2 %0, %4, off sc0\n\t"
              "global_load_dwordx2 %1, %5, off sc0\n\t"
              "global_load_dwordx2 %2, %6, off sc0\n\t"
              "global_load_dwordx2 %3, %7, off sc0\n\t"
              "s_waitcnt vmcnt(0)"
              : "=&v"(f0), "=&v"(f1), "=&v"(f2), "=&v"(f3)
              : "v"(q0), "v"(q1), "v"(q2), "v"(q3)
              : "memory");
            bool ok = ((unsigned)(f0 >> 32) == want) && ((unsigned)(f1 >> 32) == want) &&
                      ((unsigned)(f2 >> 32) == want) && ((unsigned)(f3 >> 32) == want);
            if (__all(ok)) { got = true; break; }
            if (s3step >= t) break;
          }
          if (got) {
            hs[p2] = LO32F(f0); hs[p2 + 128] = LO32F(f1); hs[p2 + 256] = LO32F(f2);
            if (f4) hs[p2 + 384] = LO32F(f3);
            if ((tid & 63) == 0) wflag[(tid >> 6) - 1] = t;
          }
        } else {
          const int p3 = tid - 192;
          unsigned long long w[7];
          for (;;) {
            bool ok = true;
            #pragma unroll
            for (int k = 0; k < 7; ++k) {
              int idx = p3 + 64 * k;
              if (idx < 400) { w[k] = LDA64(ssrc + idx); ok &= ((unsigned)(w[k] >> 32) == want); }
            }
            if (__all(ok)) break;
            __builtin_amdgcn_s_sleep(1);
          }
          #pragma unroll
          for (int k = 0; k < 7; ++k) {
            int idx = p3 + 64 * k;
            if (idx < 400) hs[idx] = LO32F(w[k]);
          }
          if (p3 == 0) {
            if (t == 1) mode_s = (wflag[0] == 1 && wflag[1] == 1) ? 1 : 2;
            s3step = t;
          }
        }
      }
    }
    __syncthreads();   // [1] hs ready

    float a0 = 0.f, a1 = 0.f, a2 = 0.f;
    #pragma unroll
    for (int j = 0; j < 25; ++j) {
      float hv = hs[c0 + j];
      a0 += wl[i][c0 + j] * hv;
      a1 += wl[16 + i][c0 + j] * hv;
      a2 += wl[32 + i][c0 + j] * hv;
    }
    #pragma unroll
    for (int m = 1; m <= 8; m <<= 1) {
      a0 += __shfl_xor(a0, m);
      a1 += __shfl_xor(a1, m);
      a2 += __shfl_xor(a2, m);
    }
    if (cc == 0) { ghs[i] = a0; ghs[16 + i] = a1; ghs[32 + i] = a2; }
    __syncthreads();   // [2] ghs ready

    if (tid < GRU_CHUNK) {
      float r = 1.f / (1.f + expf(-(g0r + ghs[tid] + blr)));
      float z = 1.f / (1.f + expf(-(g0z + ghs[16 + tid] + blz)));
      float n = tanhf(g0n + r * (ghs[32 + tid] + bln));
      float hprev = hs[i0 + tid];
      float hn = (1.f - z) * n + z * hprev;
      msum += hn;
      unsigned long long pk =
          ((unsigned long long)(unsigned)(t + 1) << 32) |
          (unsigned long long)__float_as_uint(hn);
      unsigned long long* fdst = fb + ((t + 1) & 1) * 400 + i0 + tid;
      asm volatile("global_store_dwordx2 %0, %1, off" :: "v"(fdst), "v"(pk) : "memory");
      __hip_atomic_store(hb + ((t + 1) & 1) * 400 + i0 + tid, pk,
                         __ATOMIC_RELAXED, __HIP_MEMORY_SCOPE_AGENT);
      enc[(size_t)t_in * 800 + dir * 400 + i0 + tid] = hn;
      g0r = g1r; g0z = g1z; g0n = g1n;
      int t2 = t + 2; if (t2 > 511) t2 = 511;
      int tn2 = dir ? (511 - t2) : t2;
      const float* g = gi + (size_t)tn2 * 2400 + dir * 1200 + i0 + tid;
      g1r = g[0]; g1z = g[400]; g1n = g[800];
    }
  }
  if (tid < GRU_CHUNK)
    mean[dir * 400 + i0 + tid] = msum * (1.f / 512.f);
}

// ---------------------------------------------------------------------------
// K6: decoder with doc + dt prologue. Parallel segment passes.
// ---------------------------------------------------------------------------
__global__ __launch_bounds__(1024, 1)
void decoder_kernel(const float* __restrict__ pre1,
                    const float* __restrict__ Qb,
                    const float* __restrict__ mean,
                    const float* __restrict__ W_doc,
                    const float* __restrict__ b_doc,
                    const float* __restrict__ W_d1,
                    const float* __restrict__ W_d2,
                    const float* __restrict__ b_d2,
                    const int* __restrict__ nos_p,
                    float* __restrict__ out)
{
  const int tid = threadIdx.x;
  const int row = tid >> 1;
  const int half = tid & 1;
  __shared__ float mean_s[800];
  __shared__ float doc_s[400];
  __shared__ float dt_s[100];
  __shared__ float q[100];
  __shared__ float w2s[100];
  __shared__ int   selfl[512];
  __shared__ int   firstpos;
  __shared__ float red[16];

  if (tid < 800) mean_s[tid] = mean[tid];
  if (tid < 100) { q[tid] = 0.f; w2s[tid] = W_d2[tid]; }
  if (tid < 512) selfl[tid] = 0;
  __syncthreads();

  const int w = tid >> 6, l = tid & 63;
  for (int rr = 0; rr < 25; ++rr) {
    int r = w * 25 + rr;
    float s = 0.f;
    for (int k = l; k < 800; k += 64) s += W_doc[(size_t)r * 800 + k] * mean_s[k];
    s += __shfl_xor(s, 1);  s += __shfl_xor(s, 2);  s += __shfl_xor(s, 4);
    s += __shfl_xor(s, 8);  s += __shfl_xor(s, 16); s += __shfl_xor(s, 32);
    if (l == 0) doc_s[r] = tanhf(s + b_doc[r]);
  }
  __syncthreads();
  for (int r = w; r < 100; r += 16) {
    float s = 0.f;
    for (int k = l; k < 400; k += 64) s += W_d1[(size_t)r * 1600 + 1200 + k] * doc_s[k];
    s += __shfl_xor(s, 1);  s += __shfl_xor(s, 2);  s += __shfl_xor(s, 4);
    s += __shfl_xor(s, 8);  s += __shfl_xor(s, 16); s += __shfl_xor(s, 32);
    if (l == 0) dt_s[r] = s;
  }
  __syncthreads();

  float pr[50];
  #pragma unroll
  for (int k = 0; k < 50; ++k)
    pr[k] = pre1[(size_t)row * 100 + half * 50 + k] + dt_s[half * 50 + k];
  const float bd2 = b_d2[0];
  const int nos = nos_p[0];
  int count = 0, seg = 0;
  float logp_part = 0.f;
  __syncthreads();

  for (int pass = 0; pass < 600 && seg < 512; ++pass) {
    const bool allowed = (nos <= 0) || (count < nos);
    if (tid == 0) firstpos = 512;
    float acc = 0.f;
    #pragma unroll
    for (int k = 0; k < 50; ++k)
      acc += w2s[half * 50 + k] * tanhf(pr[k] + q[half * 50 + k]);
    acc += __shfl_xor(acc, 1);
    const float sv = acc + bd2;
    __syncthreads();
    if (allowed && half == 0 && row >= seg && sv > 0.f)
      atomicMin(&firstpos, row);
    __syncthreads();
    const int fp = allowed ? firstpos : 512;
    const int lim = (fp < 512) ? fp : 511;
    if (half == 0 && row >= seg && row <= lim) {
      float p = 1.f / (1.f + expf(-sv));
      float term = (row == fp) ? p : (1.f - p);
      logp_part += logf(term * 0.99999f + 5e-6f);
      if (row == fp) selfl[row] = 1;
    }
    if (fp < 512) {
      if (tid < 100) q[tid] += Qb[(size_t)fp * 100 + tid];
      count += 1;
      seg = fp + 1;
    } else {
      seg = 512;
    }
    __syncthreads();
  }

  float v = logp_part;
  v += __shfl_xor(v, 1);  v += __shfl_xor(v, 2);  v += __shfl_xor(v, 4);
  v += __shfl_xor(v, 8);  v += __shfl_xor(v, 16); v += __shfl_xor(v, 32);
  if ((tid & 63) == 0) red[tid >> 6] = v;
  __syncthreads();
  if (tid == 0) {
    float s = 0.f;
    #pragma unroll
    for (int ww = 0; ww < 16; ++ww) s += red[ww];
    out[0] = s;
  }
  if (half == 0) out[1 + row] = (float)selfl[row];
}

// ---------------------------------------------------------------------------
// Launcher. Fast path (ws >= 12.1 MB): r12 layout + fbuf/ctl in dead region.
// ---------------------------------------------------------------------------
extern "C" void kernel_launch(void* const* d_in, const int* in_sizes, int n_in,
                              void* d_out, int out_size, void* d_ws, size_t ws_size,
                              hipStream_t stream) {
  const int*   x      = (const int*)  d_in[0];
  const int*   nos    = (const int*)  d_in[1];
  const float* emb    = (const float*)d_in[2];
  const float* cw[8];
  for (int k = 0; k < 8; ++k) cw[k] = (const float*)d_in[3 + k];
  const float* conv_b = (const float*)d_in[11];
  const float* w_ih_f = (const float*)d_in[12];
  const float* w_hh_f = (const float*)d_in[13];
  const float* b_ih_f = (const float*)d_in[14];
  const float* b_hh_f = (const float*)d_in[15];
  const float* w_ih_b = (const float*)d_in[16];
  const float* w_hh_b = (const float*)d_in[17];
  const float* b_ih_b = (const float*)d_in[18];
  const float* b_hh_b = (const float*)d_in[19];
  const float* W_doc  = (const float*)d_in[20];
  const float* b_doc  = (const float*)d_in[21];
  const float* W_d1   = (const float*)d_in[22];
  const float* b_d1   = (const float*)d_in[23];
  const float* W_d2   = (const float*)d_in[24];
  const float* b_d2   = (const float*)d_in[25];
  const float* W_r    = (const float*)d_in[26];
  const float* b_r    = (const float*)d_in[27];

  float* ws = (float*)d_ws;
  const size_t NEED_FAST = (size_t)3009664 * 4;   // bytes

  if (ws_size >= NEED_FAST) {
    float* Awin   = ws;                      // [512][3072]
    float* Wpad   = ws + 1572864;            // [400][3072] -> enc later
    float* pooled = ws + 2801664;            // [512][400]  -> pre1 later
    float* gi     = ws;                      // (Awin dead)
    unsigned long long* hbuf = (unsigned long long*)(ws + 3006464);  // 1600 u64
    unsigned long long* fbuf = (unsigned long long*)(ws + 2000000);  // 1600 u64 (dead Wpad tail)
    unsigned int* ctl = (unsigned int*)(ws + 2003200);               // 16 u32
    float* enc    = ws + 1572864;            // (Wpad dead)
    float* mean   = ws + 1982464;            // 800
    float* Rbuf   = ws;                      // (gi dead after GRU)
    float* Qbuf   = ws + 204800;
    float* pre1   = ws + 2801664;            // (pooled dead after gemm_gi)

    window_kernel<<<512, 256, 0, stream>>>(x, emb, Awin, 3072);
    pad_kernel<<<400, 256, 0, stream>>>(cw[0], cw[1], cw[2], cw[3],
                                        cw[4], cw[5], cw[6], cw[7], Wpad);
    gemm32<0><<<dim3(13, 16), 256, 0, stream>>>(Awin, 3072, Wpad, 3072, conv_b,
                                                pooled, 400, 512, 400, 3072, 0);
    gemm_gi<<<dim3(38, 8), 256, 0, stream>>>(pooled, w_ih_f, b_ih_f, w_ih_b, b_ih_b,
                                             gi, hbuf, (unsigned long long*)fbuf);
    gru_scan_kernel<<<1024, 256, 0, stream>>>(gi, w_hh_f, b_hh_f, w_hh_b, b_hh_b,
                                              enc, mean, hbuf, fbuf, ctl);
    gemm32<1><<<dim3(13, 16), 256, 0, stream>>>(enc, 800, W_r, 800, b_r,
                                                Rbuf, 400, 512, 400, 800, 1);
    gemm32<2><<<dim3(4, 16), 256, 0, stream>>>(Rbuf, 400, W_d1 + 800, 1600, nullptr,
                                               Qbuf, 100, 512, 100, 400, 0);
    gemm32<3><<<dim3(4, 16), 256, 0, stream>>>(enc, 800, W_d1, 1600, b_d1,
                                               pre1, 100, 512, 100, 800, 0);
    decoder_kernel<<<1, 1024, 0, stream>>>(pre1, Qbuf, mean, W_doc, b_doc, W_d1,
                                           W_d2, b_d2, nos, (float*)d_out);
  } else {
    // fallback: r10 layout + on-the-fly gemm_pool
    float* Awin   = ws;
    float* gi     = ws;
    float* Rbuf   = ws;
    float* Qbuf   = ws + 204800;
    unsigned long long* hbuf = (unsigned long long*)(ws + 1228800);
    unsigned long long* fbuf = (unsigned long long*)(ws + 1232000);
    unsigned int* ctl = (unsigned int*)(ws + 1235200);
    float* pooled = ws + 1536000;
    float* pre1   = ws + 1536000;
    float* mean   = ws + 1587200;
    float* enc    = ws + 1740800;

    window_kernel<<<512, 256, 0, stream>>>(x, emb, Awin, 3000);
    gemm_pool<<<dim3(7, 8), 256, 0, stream>>>(Awin, cw[0], cw[1], cw[2], cw[3],
                                              cw[4], cw[5], cw[6], cw[7],
                                              conv_b, pooled);
    gemm_gi<<<dim3(38, 8), 256, 0, stream>>>(pooled, w_ih_f, b_ih_f, w_ih_b, b_ih_b,
                                             gi, hbuf, fbuf);
    gru_scan_kernel<<<1024, 256, 0, stream>>>(gi, w_hh_f, b_hh_f, w_hh_b, b_hh_b,
                                              enc, mean, hbuf, fbuf, ctl);
    gemm32<1><<<dim3(13, 16), 256, 0, stream>>>(enc, 800, W_r, 800, b_r,
                                                Rbuf, 400, 512, 400, 800, 1);
    gemm32<2><<<dim3(4, 16), 256, 0, stream>>>(Rbuf, 400, W_d1 + 800, 1600, nullptr,
                                               Qbuf, 100, 512, 100, 400, 0);
    gemm32<3><<<dim3(4, 16), 256, 0, stream>>>(enc, 800, W_d1, 1600, b_d1,
                                               pre1, 100, 512, 100, 800, 0);
    decoder_kernel<<<1, 1024, 0, stream>>>(pre1, Qbuf, mean, W_doc, b_doc, W_d1,
                                           W_d2, b_d2, nos, (float*)d_out);
  }
}

// Round 14
// 2020.798 us; speedup vs baseline: 1.0286x; 1.0286x over previous
//
#include <hip/hip_runtime.h>
#include <math.h>

// Problem dims
#define S_N   512
#define WL_N  100
#define E_N   200
#define OC_N  50
#define H_N   400

// ---------------------------------------------------------------------------
// K1a: window_kernel — Awin[s][dd*200+e] = (1/L)*sum_{t<L} in[e][t+(dd-7)]
// ---------------------------------------------------------------------------
__global__ __launch_bounds__(256, 1)
void window_kernel(const int* __restrict__ x, const float* __restrict__ emb,
                   float* __restrict__ Awin, int stride)
{
  const int s = blockIdx.x;
  const int tid = threadIdx.x;
  __shared__ int xr[WL_N];
  __shared__ int Lsh;
  __shared__ float Apart[E_N][17];
  __shared__ float Bpart[E_N][9];
  if (tid < WL_N) xr[tid] = x[s * WL_N + tid];
  for (int idx = tid; idx < stride - 3000; idx += 256)
    Awin[(size_t)s * stride + 3000 + idx] = 0.f;
  __syncthreads();
  if (tid == 0) {
    int L = 0;
    for (int t = 0; t < WL_N; ++t) L += (xr[t] != 0) ? 1 : 0;
    Lsh = L;
  }
  __syncthreads();
  const int L = Lsh;  // in [20,100]
  const int Lp7 = (L + 7 < WL_N) ? (L + 7) : WL_N;
  if (tid < E_N) {
    const int e = tid;
    float acc = 0.f;
    for (int t = 0; t < Lp7; ++t) {
      acc += emb[(size_t)xr[t] * E_N + e];
      int m = t + 1;
      if (m <= 7) Bpart[e][m] = acc;
      int rel = m - (L - 7);
      if (rel >= 0 && rel < 15) Apart[e][rel] = acc;
    }
    const float accF = acc;
    const float invL = 1.f / (float)L;
    #pragma unroll
    for (int dd = 0; dd < 15; ++dd) {
      int m = L - 7 + dd;
      float A = (m > WL_N) ? accF : Apart[e][dd];
      int d = dd - 7;
      float B = (d > 0) ? Bpart[e][d] : 0.f;
      Awin[(size_t)s * stride + dd * 200 + e] = (A - B) * invL;
    }
  }
}

// ---------------------------------------------------------------------------
// K1b-fast: pad_kernel — Wpad[400][3072] materialized padded conv weights
// ---------------------------------------------------------------------------
__global__ __launch_bounds__(256, 4)
void pad_kernel(const float* __restrict__ cw0, const float* __restrict__ cw1,
                const float* __restrict__ cw2, const float* __restrict__ cw3,
                const float* __restrict__ cw4, const float* __restrict__ cw5,
                const float* __restrict__ cw6, const float* __restrict__ cw7,
                float* __restrict__ Wpad)
{
  const int gcol = blockIdx.x;
  const int tid = threadIdx.x;
  const float* cwA[8] = {cw0, cw1, cw2, cw3, cw4, cw5, cw6, cw7};
  const int K = gcol / 50, oc = gcol % 50;
  const int width = 2 * K + 1;
  const int lo = 7 - K;
  const float* base = cwA[K] + (size_t)oc * 200 * width;
  for (int k = tid; k < 3072; k += 256) {
    float v = 0.f;
    if (k < 3000) {
      int dd = k / 200, e = k - dd * 200;
      int off = dd - lo;
      if (off >= 0 && off < width) v = base[e * width + off];
    }
    Wpad[(size_t)gcol * 3072 + k] = v;
  }
}

// ---------------------------------------------------------------------------
// K1b-fallback: gemm_pool on-the-fly (r10-proven; used only if ws too small)
// ---------------------------------------------------------------------------
__global__ __launch_bounds__(256, 2)
void gemm_pool(const float* __restrict__ Awin,
               const float* __restrict__ cw0, const float* __restrict__ cw1,
               const float* __restrict__ cw2, const float* __restrict__ cw3,
               const float* __restrict__ cw4, const float* __restrict__ cw5,
               const float* __restrict__ cw6, const float* __restrict__ cw7,
               const float* __restrict__ conv_b,
               float* __restrict__ pooled)
{
  __shared__ float As[16][65];
  __shared__ float Bs[16][65];
  const int bm = blockIdx.y * 64, bn = blockIdx.x * 64;
  const int tid = threadIdx.x;
  const int tr = (tid / 16) * 4, tc = (tid % 16) * 4;
  const int c = tid & 15;

  const float* cwA[8] = {cw0, cw1, cw2, cw3, cw4, cw5, cw6, cw7};
  const float* base_i[4];
  int lo_i[4], w_i[4];
  bool valid_i[4];
  #pragma unroll
  for (int i = 0; i < 4; ++i) {
    int gcol = bn + (tid >> 4) + 16 * i;
    bool v = (gcol < 400);
    int g = v ? gcol : 0;
    int K = g / 50, oc = g % 50;
    int width = 2 * K + 1;
    valid_i[i] = v;
    lo_i[i] = 7 - K;
    w_i[i] = width;
    base_i[i] = cwA[K] + (size_t)oc * 200 * width;
  }

  float acc[4][4] = {};
  int e = c, dd = 0;
  for (int k0 = 0; k0 < 3000; k0 += 16) {
    for (int l = tid; l < 64 * 16; l += 256) {
      int r = l >> 4, cc2 = l & 15;
      int k = k0 + cc2;
      As[cc2][r] = (k < 3000) ? Awin[(size_t)(bm + r) * 3000 + k] : 0.f;
    }
    #pragma unroll
    for (int i = 0; i < 4; ++i) {
      int r = (tid >> 4) + 16 * i;
      int off = dd - lo_i[i];
      float v = 0.f;
      if (valid_i[i] && off >= 0 && off < w_i[i])
        v = base_i[i][e * w_i[i] + off];
      Bs[c][r] = v;
    }
    __syncthreads();
    #pragma unroll
    for (int kk = 0; kk < 16; ++kk) {
      float a[4], b[4];
      #pragma unroll
      for (int u = 0; u < 4; ++u) { a[u] = As[kk][tr + u]; b[u] = Bs[kk][tc + u]; }
      #pragma unroll
      for (int u = 0; u < 4; ++u)
        #pragma unroll
        for (int v = 0; v < 4; ++v) acc[u][v] += a[u] * b[v];
    }
    __syncthreads();
    e += 16;
    if (e >= 200) { e -= 200; dd += 1; }
  }
  for (int u = 0; u < 4; ++u) {
    int r = bm + tr + u;
    for (int v = 0; v < 4; ++v) {
      int cc2 = bn + tc + v; if (cc2 >= 400) continue;
      pooled[(size_t)r * 400 + cc2] = acc[u][v] + conv_b[cc2];
    }
  }
}

// ---------------------------------------------------------------------------
// K2: gemm_gi (+ zero hbuf in block (0,0)) — r12-proven
// ---------------------------------------------------------------------------
__global__ __launch_bounds__(256, 2)
void gemm_gi(const float* __restrict__ A,
             const float* __restrict__ wf, const float* __restrict__ bf,
             const float* __restrict__ wb, const float* __restrict__ bb,
             float* __restrict__ C,
             unsigned long long* __restrict__ hz)
{
  __shared__ float As[16][65];
  __shared__ float Bs[16][65];
  const int bm = blockIdx.y * 64, bn = blockIdx.x * 64;
  const int tid = threadIdx.x;
  const int tr = (tid / 16) * 4, tc = (tid % 16) * 4;
  if (blockIdx.x == 0 && blockIdx.y == 0)
    for (int l = tid; l < 1600; l += 256) hz[l] = 0ull;
  float acc[4][4] = {};
  for (int k0 = 0; k0 < 400; k0 += 16) {
    for (int l = tid; l < 64 * 16; l += 256) {
      int r = l / 16, c = l % 16;
      As[c][r] = A[(size_t)(bm + r) * 400 + k0 + c];
    }
    for (int l = tid; l < 64 * 16; l += 256) {
      int r = l / 16, c = l % 16;
      int gcol = bn + r;
      float v = 0.f;
      if (gcol < 1200)      v = wf[(size_t)gcol * 400 + k0 + c];
      else if (gcol < 2400) v = wb[(size_t)(gcol - 1200) * 400 + k0 + c];
      Bs[c][r] = v;
    }
    __syncthreads();
    #pragma unroll
    for (int kk = 0; kk < 16; ++kk) {
      float a[4], b[4];
      #pragma unroll
      for (int u = 0; u < 4; ++u) { a[u] = As[kk][tr + u]; b[u] = Bs[kk][tc + u]; }
      #pragma unroll
      for (int u = 0; u < 4; ++u)
        #pragma unroll
        for (int v = 0; v < 4; ++v) acc[u][v] += a[u] * b[v];
    }
    __syncthreads();
  }
  for (int u = 0; u < 4; ++u) {
    int r = bm + tr + u;
    for (int v = 0; v < 4; ++v) {
      int c = bn + tc + v; if (c >= 2400) continue;
      float bias = (c < 1200) ? bf[c] : bb[c - 1200];
      C[(size_t)r * 2400 + c] = acc[u][v] + bias;
    }
  }
}

// ---------------------------------------------------------------------------
// gemm64: generic 64x64-tile / 4x4-acc GEMM (gemm_gi-style, N/K guarded).
// C[M,N] = A[M,K] @ B[N,K]^T + bias (optional tanh). M multiple of 64.
// ---------------------------------------------------------------------------
template<int TAG>
__global__ __launch_bounds__(256, 2)
void gemm64(const float* __restrict__ A, int lda,
            const float* __restrict__ Bw, int ldb,
            const float* __restrict__ bias,
            float* __restrict__ C, int ldc,
            int M, int N, int K, int act)
{
  __shared__ float As[16][65];
  __shared__ float Bs[16][65];
  const int bm = blockIdx.y * 64, bn = blockIdx.x * 64;
  const int tid = threadIdx.x;
  const int tr = (tid / 16) * 4, tc = (tid % 16) * 4;
  float acc[4][4] = {};
  for (int k0 = 0; k0 < K; k0 += 16) {
    for (int l = tid; l < 64 * 16; l += 256) {
      int r = l / 16, c = l % 16;
      As[c][r] = A[(size_t)(bm + r) * lda + k0 + c];
    }
    for (int l = tid; l < 64 * 16; l += 256) {
      int r = l / 16, c = l % 16;
      int gcol = bn + r;
      Bs[c][r] = (gcol < N) ? Bw[(size_t)gcol * ldb + k0 + c] : 0.f;
    }
    __syncthreads();
    #pragma unroll
    for (int kk = 0; kk < 16; ++kk) {
      float a[4], b[4];
      #pragma unroll
      for (int u = 0; u < 4; ++u) { a[u] = As[kk][tr + u]; b[u] = Bs[kk][tc + u]; }
      #pragma unroll
      for (int u = 0; u < 4; ++u)
        #pragma unroll
        for (int v = 0; v < 4; ++v) acc[u][v] += a[u] * b[v];
    }
    __syncthreads();
  }
  for (int u = 0; u < 4; ++u) {
    int r = bm + tr + u;
    for (int v = 0; v < 4; ++v) {
      int c = bn + tc + v; if (c >= N) continue;
      float xv = acc[u][v] + (bias ? bias[c] : 0.f);
      if (act == 1) xv = tanhf(xv);
      C[(size_t)r * ldc + c] = xv;
    }
  }
}

// ---------------------------------------------------------------------------
// 32x32-tile GEMM (for N=100 outputs): C = A@B^T + bias
// ---------------------------------------------------------------------------
template<int TAG>
__global__ __launch_bounds__(256, 4)
void gemm32(const float* __restrict__ A, int lda,
            const float* __restrict__ Bw, int ldb,
            const float* __restrict__ bias,
            float* __restrict__ C, int ldc,
            int M, int N, int K, int act)
{
  __shared__ float As[32][33];
  __shared__ float Bs[32][33];
  const int bm = blockIdx.y * 32, bn = blockIdx.x * 32;
  const int tid = threadIdx.x;
  const int tr = (tid >> 4) * 2, tc = (tid & 15) * 2;
  float acc[2][2] = {};
  for (int k0 = 0; k0 < K; k0 += 32) {
    #pragma unroll
    for (int p = 0; p < 4; ++p) {
      int l = tid + p * 256;
      int r = l >> 5, c = l & 31;
      As[c][r] = (bm + r < M) ? A[(size_t)(bm + r) * lda + k0 + c] : 0.f;
      Bs[c][r] = (bn + r < N) ? Bw[(size_t)(bn + r) * ldb + k0 + c] : 0.f;
    }
    __syncthreads();
    #pragma unroll
    for (int kk = 0; kk < 32; ++kk) {
      float a0 = As[kk][tr], a1 = As[kk][tr + 1];
      float b0 = Bs[kk][tc], b1 = Bs[kk][tc + 1];
      acc[0][0] += a0 * b0; acc[0][1] += a0 * b1;
      acc[1][0] += a1 * b0; acc[1][1] += a1 * b1;
    }
    __syncthreads();
  }
  #pragma unroll
  for (int u = 0; u < 2; ++u) {
    int r = bm + tr + u; if (r >= M) continue;
    #pragma unroll
    for (int v = 0; v < 2; ++v) {
      int c = bn + tc + v; if (c >= N) continue;
      float xv = acc[u][v] + (bias ? bias[c] : 0.f);
      if (act == 1) xv = tanhf(xv);
      C[(size_t)r * ldc + c] = xv;
    }
  }
}

// ---------------------------------------------------------------------------
// K3: bidirectional GRU scan — EXACT r12 kernel (role-split, 1065us floor)
// ---------------------------------------------------------------------------
#define GRU_NB 25
#define GRU_CHUNK 16
#define LDA64(p) __hip_atomic_load((p), __ATOMIC_RELAXED, __HIP_MEMORY_SCOPE_AGENT)
__global__ __launch_bounds__(256, 1)
void gru_scan_kernel(const float* __restrict__ gi,
                     const float* __restrict__ whh_f, const float* __restrict__ bhh_f,
                     const float* __restrict__ whh_b, const float* __restrict__ bhh_b,
                     float* __restrict__ enc,
                     float* __restrict__ mean,
                     unsigned long long* __restrict__ hbuf)
{
  const int tid = threadIdx.x;
  const int dir = blockIdx.x / GRU_NB;
  const int b   = blockIdx.x % GRU_NB;
  const float* whh = dir ? whh_b : whh_f;
  const float* bhh = dir ? bhh_b : bhh_f;
  unsigned long long* hb = hbuf + (size_t)dir * 800;
  const int i0 = b * GRU_CHUNK;

  __shared__ float wl[48][400];
  __shared__ float hs[400];
  __shared__ float ghs[48];

  for (int l = tid; l < 48 * 400; l += 256) {
    int lr = l / 400, c = l % 400;
    int g = lr / GRU_CHUNK, ii = lr % GRU_CHUNK;
    wl[lr][c] = whh[(size_t)(g * 400 + i0 + ii) * 400 + c];
  }

  const int i  = tid >> 4;
  const int cc = tid & 15;
  const int c0 = cc * 25;

  float blr = 0.f, blz = 0.f, bln = 0.f, msum = 0.f;
  float g0r = 0.f, g0z = 0.f, g0n = 0.f;
  float g1r = 0.f, g1z = 0.f, g1n = 0.f;
  if (tid < GRU_CHUNK) {
    blr = bhh[i0 + tid];
    blz = bhh[400 + i0 + tid];
    bln = bhh[800 + i0 + tid];
    {
      int t0 = dir ? 511 : 0;
      const float* g = gi + (size_t)t0 * 2400 + dir * 1200 + i0 + tid;
      g0r = g[0]; g0z = g[400]; g0n = g[800];
      int t1 = dir ? 510 : 1;
      g = gi + (size_t)t1 * 2400 + dir * 1200 + i0 + tid;
      g1r = g[0]; g1z = g[400]; g1n = g[800];
    }
  }
  __syncthreads();

  const int p = tid - 64;
  const bool h2 = (p >= 0) && (p < 16);

  for (int t = 0; t < 512; ++t) {
    const int t_in = dir ? (511 - t) : t;
    if (tid >= 64) {
      const unsigned long long* src = hb + (t & 1) * 400;
      const unsigned want = (unsigned)t;
      unsigned long long a0, a1, a2 = 0, b0, b1, b2 = 0, r0, r1, r2 = 0;
      a0 = LDA64(src + p); a1 = LDA64(src + p + 192); if (h2) a2 = LDA64(src + p + 384);
      b0 = LDA64(src + p); b1 = LDA64(src + p + 192); if (h2) b2 = LDA64(src + p + 384);
      for (;;) {
        bool ok = ((unsigned)(a0 >> 32) == want) && ((unsigned)(a1 >> 32) == want)
                  && (!h2 || ((unsigned)(a2 >> 32) == want));
        if (__all(ok)) { r0 = a0; r1 = a1; r2 = a2; break; }
        a0 = LDA64(src + p); a1 = LDA64(src + p + 192); if (h2) a2 = LDA64(src + p + 384);
        ok = ((unsigned)(b0 >> 32) == want) && ((unsigned)(b1 >> 32) == want)
             && (!h2 || ((unsigned)(b2 >> 32) == want));
        if (__all(ok)) { r0 = b0; r1 = b1; r2 = b2; break; }
        b0 = LDA64(src + p); b1 = LDA64(src + p + 192); if (h2) b2 = LDA64(src + p + 384);
      }
      hs[p] = __uint_as_float((unsigned)r0);
      hs[p + 192] = __uint_as_float((unsigned)r1);
      if (h2) hs[p + 384] = __uint_as_float((unsigned)r2);
    }
    __syncthreads();   // [1] hs ready

    float a0 = 0.f, a1 = 0.f, a2 = 0.f;
    #pragma unroll
    for (int j = 0; j < 25; ++j) {
      float hv = hs[c0 + j];
      a0 += wl[i][c0 + j] * hv;
      a1 += wl[16 + i][c0 + j] * hv;
      a2 += wl[32 + i][c0 + j] * hv;
    }
    #pragma unroll
    for (int m = 1; m <= 8; m <<= 1) {
      a0 += __shfl_xor(a0, m);
      a1 += __shfl_xor(a1, m);
      a2 += __shfl_xor(a2, m);
    }
    if (cc == 0) { ghs[i] = a0; ghs[16 + i] = a1; ghs[32 + i] = a2; }
    __syncthreads();   // [2] ghs ready

    if (tid < GRU_CHUNK) {
      float r = 1.f / (1.f + expf(-(g0r + ghs[tid] + blr)));
      float z = 1.f / (1.f + expf(-(g0z + ghs[16 + tid] + blz)));
      float n = tanhf(g0n + r * (ghs[32 + tid] + bln));
      float hprev = hs[i0 + tid];
      float hn = (1.f - z) * n + z * hprev;
      msum += hn;
      unsigned long long pk =
          ((unsigned long long)(unsigned)(t + 1) << 32) |
          (unsigned long long)__float_as_uint(hn);
      __hip_atomic_store(hb + ((t + 1) & 1) * 400 + i0 + tid, pk,
                         __ATOMIC_RELAXED, __HIP_MEMORY_SCOPE_AGENT);
      enc[(size_t)t_in * 800 + dir * 400 + i0 + tid] = hn;
      g0r = g1r; g0z = g1z; g0n = g1n;
      int t2 = t + 2; if (t2 > 511) t2 = 511;
      int tn2 = dir ? (511 - t2) : t2;
      const float* g = gi + (size_t)tn2 * 2400 + dir * 1200 + i0 + tid;
      g1r = g[0]; g1z = g[400]; g1n = g[800];
    }
  }
  if (tid < GRU_CHUNK)
    mean[dir * 400 + i0 + tid] = msum * (1.f / 512.f);
}

// ---------------------------------------------------------------------------
// K6: decoder with doc + dt prologue. Parallel segment passes.
// ---------------------------------------------------------------------------
__global__ __launch_bounds__(1024, 1)
void decoder_kernel(const float* __restrict__ pre1,
                    const float* __restrict__ Qb,
                    const float* __restrict__ mean,
                    const float* __restrict__ W_doc,
                    const float* __restrict__ b_doc,
                    const float* __restrict__ W_d1,
                    const float* __restrict__ W_d2,
                    const float* __restrict__ b_d2,
                    const int* __restrict__ nos_p,
                    float* __restrict__ out)
{
  const int tid = threadIdx.x;
  const int row = tid >> 1;
  const int half = tid & 1;
  __shared__ float mean_s[800];
  __shared__ float doc_s[400];
  __shared__ float dt_s[100];
  __shared__ float q[100];
  __shared__ float w2s[100];
  __shared__ int   selfl[512];
  __shared__ int   firstpos;
  __shared__ float red[16];

  if (tid < 800) mean_s[tid] = mean[tid];
  if (tid < 100) { q[tid] = 0.f; w2s[tid] = W_d2[tid]; }
  if (tid < 512) selfl[tid] = 0;
  __syncthreads();

  const int w = tid >> 6, l = tid & 63;
  for (int rr = 0; rr < 25; ++rr) {
    int r = w * 25 + rr;
    float s = 0.f;
    for (int k = l; k < 800; k += 64) s += W_doc[(size_t)r * 800 + k] * mean_s[k];
    s += __shfl_xor(s, 1);  s += __shfl_xor(s, 2);  s += __shfl_xor(s, 4);
    s += __shfl_xor(s, 8);  s += __shfl_xor(s, 16); s += __shfl_xor(s, 32);
    if (l == 0) doc_s[r] = tanhf(s + b_doc[r]);
  }
  __syncthreads();
  for (int r = w; r < 100; r += 16) {
    float s = 0.f;
    for (int k = l; k < 400; k += 64) s += W_d1[(size_t)r * 1600 + 1200 + k] * doc_s[k];
    s += __shfl_xor(s, 1);  s += __shfl_xor(s, 2);  s += __shfl_xor(s, 4);
    s += __shfl_xor(s, 8);  s += __shfl_xor(s, 16); s += __shfl_xor(s, 32);
    if (l == 0) dt_s[r] = s;
  }
  __syncthreads();

  float pr[50];
  #pragma unroll
  for (int k = 0; k < 50; ++k)
    pr[k] = pre1[(size_t)row * 100 + half * 50 + k] + dt_s[half * 50 + k];
  const float bd2 = b_d2[0];
  const int nos = nos_p[0];
  int count = 0, seg = 0;
  float logp_part = 0.f;
  __syncthreads();

  for (int pass = 0; pass < 600 && seg < 512; ++pass) {
    const bool allowed = (nos <= 0) || (count < nos);
    if (tid == 0) firstpos = 512;
    float acc = 0.f;
    #pragma unroll
    for (int k = 0; k < 50; ++k)
      acc += w2s[half * 50 + k] * tanhf(pr[k] + q[half * 50 + k]);
    acc += __shfl_xor(acc, 1);
    const float sv = acc + bd2;
    __syncthreads();
    if (allowed && half == 0 && row >= seg && sv > 0.f)
      atomicMin(&firstpos, row);
    __syncthreads();
    const int fp = allowed ? firstpos : 512;
    const int lim = (fp < 512) ? fp : 511;
    if (half == 0 && row >= seg && row <= lim) {
      float p = 1.f / (1.f + expf(-sv));
      float term = (row == fp) ? p : (1.f - p);
      logp_part += logf(term * 0.99999f + 5e-6f);
      if (row == fp) selfl[row] = 1;
    }
    if (fp < 512) {
      if (tid < 100) q[tid] += Qb[(size_t)fp * 100 + tid];
      count += 1;
      seg = fp + 1;
    } else {
      seg = 512;
    }
    __syncthreads();
  }

  float v = logp_part;
  v += __shfl_xor(v, 1);  v += __shfl_xor(v, 2);  v += __shfl_xor(v, 4);
  v += __shfl_xor(v, 8);  v += __shfl_xor(v, 16); v += __shfl_xor(v, 32);
  if ((tid & 63) == 0) red[tid >> 6] = v;
  __syncthreads();
  if (tid == 0) {
    float s = 0.f;
    #pragma unroll
    for (int ww = 0; ww < 16; ++ww) s += red[ww];
    out[0] = s;
  }
  if (half == 0) out[1 + row] = (float)selfl[row];
}

// ---------------------------------------------------------------------------
// Launcher. Fast path (ws >= 12.1 MB): r12 layout, gemm64 for pooled & R.
// ---------------------------------------------------------------------------
extern "C" void kernel_launch(void* const* d_in, const int* in_sizes, int n_in,
                              void* d_out, int out_size, void* d_ws, size_t ws_size,
                              hipStream_t stream) {
  const int*   x      = (const int*)  d_in[0];
  const int*   nos    = (const int*)  d_in[1];
  const float* emb    = (const float*)d_in[2];
  const float* cw[8];
  for (int k = 0; k < 8; ++k) cw[k] = (const float*)d_in[3 + k];
  const float* conv_b = (const float*)d_in[11];
  const float* w_ih_f = (const float*)d_in[12];
  const float* w_hh_f = (const float*)d_in[13];
  const float* b_ih_f = (const float*)d_in[14];
  const float* b_hh_f = (const float*)d_in[15];
  const float* w_ih_b = (const float*)d_in[16];
  const float* w_hh_b = (const float*)d_in[17];
  const float* b_ih_b = (const float*)d_in[18];
  const float* b_hh_b = (const float*)d_in[19];
  const float* W_doc  = (const float*)d_in[20];
  const float* b_doc  = (const float*)d_in[21];
  const float* W_d1   = (const float*)d_in[22];
  const float* b_d1   = (const float*)d_in[23];
  const float* W_d2   = (const float*)d_in[24];
  const float* b_d2   = (const float*)d_in[25];
  const float* W_r    = (const float*)d_in[26];
  const float* b_r    = (const float*)d_in[27];

  float* ws = (float*)d_ws;
  const size_t NEED_FAST = (size_t)3009664 * 4;   // bytes

  if (ws_size >= NEED_FAST) {
    float* Awin   = ws;                      // [512][3072]
    float* Wpad   = ws + 1572864;            // [400][3072] -> enc later
    float* pooled = ws + 2801664;            // [512][400]  -> pre1 later
    float* gi     = ws;                      // (Awin dead)
    unsigned long long* hbuf = (unsigned long long*)(ws + 3006464);  // 1600 u64
    float* enc    = ws + 1572864;            // (Wpad dead)
    float* mean   = ws + 1982464;            // 800
    float* Rbuf   = ws;                      // (gi dead after GRU)
    float* Qbuf   = ws + 204800;
    float* pre1   = ws + 2801664;            // (pooled dead after gemm_gi)

    window_kernel<<<512, 256, 0, stream>>>(x, emb, Awin, 3072);
    pad_kernel<<<400, 256, 0, stream>>>(cw[0], cw[1], cw[2], cw[3],
                                        cw[4], cw[5], cw[6], cw[7], Wpad);
    // pooled = Awin @ Wpad^T + conv_b  (64x64 tile)
    gemm64<0><<<dim3(7, 8), 256, 0, stream>>>(Awin, 3072, Wpad, 3072, conv_b,
                                              pooled, 400, 512, 400, 3072, 0);
    gemm_gi<<<dim3(38, 8), 256, 0, stream>>>(pooled, w_ih_f, b_ih_f, w_ih_b, b_ih_b,
                                             gi, hbuf);
    gru_scan_kernel<<<2 * GRU_NB, 256, 0, stream>>>(gi, w_hh_f, b_hh_f, w_hh_b, b_hh_b,
                                                    enc, mean, hbuf);
    // R = tanh(enc @ W_r^T + b_r)  (64x64 tile)
    gemm64<1><<<dim3(7, 8), 256, 0, stream>>>(enc, 800, W_r, 800, b_r,
                                              Rbuf, 400, 512, 400, 800, 1);
    gemm32<2><<<dim3(4, 16), 256, 0, stream>>>(Rbuf, 400, W_d1 + 800, 1600, nullptr,
                                               Qbuf, 100, 512, 100, 400, 0);
    gemm32<3><<<dim3(4, 16), 256, 0, stream>>>(enc, 800, W_d1, 1600, b_d1,
                                               pre1, 100, 512, 100, 800, 0);
    decoder_kernel<<<1, 1024, 0, stream>>>(pre1, Qbuf, mean, W_doc, b_doc, W_d1,
                                           W_d2, b_d2, nos, (float*)d_out);
  } else {
    // fallback: r10 layout + on-the-fly gemm_pool
    float* Awin   = ws;
    float* gi     = ws;
    float* Rbuf   = ws;
    float* Qbuf   = ws + 204800;
    unsigned long long* hbuf = (unsigned long long*)(ws + 1228800);
    float* pooled = ws + 1536000;
    float* pre1   = ws + 1536000;
    float* mean   = ws + 1587200;
    float* enc    = ws + 1740800;

    window_kernel<<<512, 256, 0, stream>>>(x, emb, Awin, 3000);
    gemm_pool<<<dim3(7, 8), 256, 0, stream>>>(Awin, cw[0], cw[1], cw[2], cw[3],
                                              cw[4], cw[5], cw[6], cw[7],
                                              conv_b, pooled);
    gemm_gi<<<dim3(38, 8), 256, 0, stream>>>(pooled, w_ih_f, b_ih_f, w_ih_b, b_ih_b,
                                             gi, hbuf);
    gru_scan_kernel<<<2 * GRU_NB, 256, 0, stream>>>(gi, w_hh_f, b_hh_f, w_hh_b, b_hh_b,
                                                    enc, mean, hbuf);
    gemm64<1><<<dim3(7, 8), 256, 0, stream>>>(enc, 800, W_r, 800, b_r,
                                              Rbuf, 400, 512, 400, 800, 1);
    gemm32<2><<<dim3(4, 16), 256, 0, stream>>>(Rbuf, 400, W_d1 + 800, 1600, nullptr,
                                               Qbuf, 100, 512, 100, 400, 0);
    gemm32<3><<<dim3(4, 16), 256, 0, stream>>>(enc, 800, W_d1, 1600, b_d1,
                                               pre1, 100, 512, 100, 800, 0);
    decoder_kernel<<<1, 1024, 0, stream>>>(pre1, Qbuf, mean, W_doc, b_doc, W_d1,
                                           W_d2, b_d2, nos, (float*)d_out);
  }
}

// Round 15
// 1742.771 us; speedup vs baseline: 1.1926x; 1.1595x over previous
//
#include <hip/hip_runtime.h>
#include <math.h>

// Problem dims
#define S_N   512
#define WL_N  100
#define E_N   200
#define OC_N  50
#define H_N   400

// ---------------------------------------------------------------------------
// K1: window_pad_kernel — blocks <512: Awin[s][dd*200+e] (r12 window body);
// blocks >=512: Wpad[gcol][3072] materialization (r12 pad body).
// ---------------------------------------------------------------------------
__global__ __launch_bounds__(256, 1)
void window_pad_kernel(const int* __restrict__ x, const float* __restrict__ emb,
                       float* __restrict__ Awin, int stride,
                       const float* __restrict__ cw0, const float* __restrict__ cw1,
                       const float* __restrict__ cw2, const float* __restrict__ cw3,
                       const float* __restrict__ cw4, const float* __restrict__ cw5,
                       const float* __restrict__ cw6, const float* __restrict__ cw7,
                       float* __restrict__ Wpad)
{
  const int tid = threadIdx.x;
  if (blockIdx.x >= 512) {
    // ---- pad body ----
    const int gcol = blockIdx.x - 512;
    const float* cwA[8] = {cw0, cw1, cw2, cw3, cw4, cw5, cw6, cw7};
    const int K = gcol / 50, oc = gcol % 50;
    const int width = 2 * K + 1;
    const int lo = 7 - K;
    const float* base = cwA[K] + (size_t)oc * 200 * width;
    for (int k = tid; k < 3072; k += 256) {
      float v = 0.f;
      if (k < 3000) {
        int dd = k / 200, e = k - dd * 200;
        int off = dd - lo;
        if (off >= 0 && off < width) v = base[e * width + off];
      }
      Wpad[(size_t)gcol * 3072 + k] = v;
    }
    return;
  }
  // ---- window body ----
  const int s = blockIdx.x;
  __shared__ int xr[WL_N];
  __shared__ int Lsh;
  __shared__ float Apart[E_N][17];
  __shared__ float Bpart[E_N][9];
  if (tid < WL_N) xr[tid] = x[s * WL_N + tid];
  for (int idx = tid; idx < stride - 3000; idx += 256)
    Awin[(size_t)s * stride + 3000 + idx] = 0.f;
  __syncthreads();
  if (tid == 0) {
    int L = 0;
    for (int t = 0; t < WL_N; ++t) L += (xr[t] != 0) ? 1 : 0;
    Lsh = L;
  }
  __syncthreads();
  const int L = Lsh;  // in [20,100]
  const int Lp7 = (L + 7 < WL_N) ? (L + 7) : WL_N;
  if (tid < E_N) {
    const int e = tid;
    float acc = 0.f;
    for (int t = 0; t < Lp7; ++t) {
      acc += emb[(size_t)xr[t] * E_N + e];
      int m = t + 1;
      if (m <= 7) Bpart[e][m] = acc;
      int rel = m - (L - 7);
      if (rel >= 0 && rel < 15) Apart[e][rel] = acc;
    }
    const float accF = acc;
    const float invL = 1.f / (float)L;
    #pragma unroll
    for (int dd = 0; dd < 15; ++dd) {
      int m = L - 7 + dd;
      float A = (m > WL_N) ? accF : Apart[e][dd];
      int d = dd - 7;
      float B = (d > 0) ? Bpart[e][d] : 0.f;
      Awin[(size_t)s * stride + dd * 200 + e] = (A - B) * invL;
    }
  }
}

// ---------------------------------------------------------------------------
// K1b-fallback: gemm_pool on-the-fly (r10-proven; used only if ws too small)
// ---------------------------------------------------------------------------
__global__ __launch_bounds__(256, 2)
void gemm_pool(const float* __restrict__ Awin,
               const float* __restrict__ cw0, const float* __restrict__ cw1,
               const float* __restrict__ cw2, const float* __restrict__ cw3,
               const float* __restrict__ cw4, const float* __restrict__ cw5,
               const float* __restrict__ cw6, const float* __restrict__ cw7,
               const float* __restrict__ conv_b,
               float* __restrict__ pooled)
{
  __shared__ float As[16][65];
  __shared__ float Bs[16][65];
  const int bm = blockIdx.y * 64, bn = blockIdx.x * 64;
  const int tid = threadIdx.x;
  const int tr = (tid / 16) * 4, tc = (tid % 16) * 4;
  const int c = tid & 15;

  const float* cwA[8] = {cw0, cw1, cw2, cw3, cw4, cw5, cw6, cw7};
  const float* base_i[4];
  int lo_i[4], w_i[4];
  bool valid_i[4];
  #pragma unroll
  for (int i = 0; i < 4; ++i) {
    int gcol = bn + (tid >> 4) + 16 * i;
    bool v = (gcol < 400);
    int g = v ? gcol : 0;
    int K = g / 50, oc = g % 50;
    int width = 2 * K + 1;
    valid_i[i] = v;
    lo_i[i] = 7 - K;
    w_i[i] = width;
    base_i[i] = cwA[K] + (size_t)oc * 200 * width;
  }

  float acc[4][4] = {};
  int e = c, dd = 0;
  for (int k0 = 0; k0 < 3000; k0 += 16) {
    for (int l = tid; l < 64 * 16; l += 256) {
      int r = l >> 4, cc2 = l & 15;
      int k = k0 + cc2;
      As[cc2][r] = (k < 3000) ? Awin[(size_t)(bm + r) * 3000 + k] : 0.f;
    }
    #pragma unroll
    for (int i = 0; i < 4; ++i) {
      int r = (tid >> 4) + 16 * i;
      int off = dd - lo_i[i];
      float v = 0.f;
      if (valid_i[i] && off >= 0 && off < w_i[i])
        v = base_i[i][e * w_i[i] + off];
      Bs[c][r] = v;
    }
    __syncthreads();
    #pragma unroll
    for (int kk = 0; kk < 16; ++kk) {
      float a[4], b[4];
      #pragma unroll
      for (int u = 0; u < 4; ++u) { a[u] = As[kk][tr + u]; b[u] = Bs[kk][tc + u]; }
      #pragma unroll
      for (int u = 0; u < 4; ++u)
        #pragma unroll
        for (int v = 0; v < 4; ++v) acc[u][v] += a[u] * b[v];
    }
    __syncthreads();
    e += 16;
    if (e >= 200) { e -= 200; dd += 1; }
  }
  for (int u = 0; u < 4; ++u) {
    int r = bm + tr + u;
    for (int v = 0; v < 4; ++v) {
      int cc2 = bn + tc + v; if (cc2 >= 400) continue;
      pooled[(size_t)r * 400 + cc2] = acc[u][v] + conv_b[cc2];
    }
  }
}

// ---------------------------------------------------------------------------
// K2: gemm_gi (+ zero hbuf in block (0,0)) — r12-proven
// ---------------------------------------------------------------------------
__global__ __launch_bounds__(256, 2)
void gemm_gi(const float* __restrict__ A,
             const float* __restrict__ wf, const float* __restrict__ bf,
             const float* __restrict__ wb, const float* __restrict__ bb,
             float* __restrict__ C,
             unsigned long long* __restrict__ hz)
{
  __shared__ float As[16][65];
  __shared__ float Bs[16][65];
  const int bm = blockIdx.y * 64, bn = blockIdx.x * 64;
  const int tid = threadIdx.x;
  const int tr = (tid / 16) * 4, tc = (tid % 16) * 4;
  if (blockIdx.x == 0 && blockIdx.y == 0)
    for (int l = tid; l < 1600; l += 256) hz[l] = 0ull;
  float acc[4][4] = {};
  for (int k0 = 0; k0 < 400; k0 += 16) {
    for (int l = tid; l < 64 * 16; l += 256) {
      int r = l / 16, c = l % 16;
      As[c][r] = A[(size_t)(bm + r) * 400 + k0 + c];
    }
    for (int l = tid; l < 64 * 16; l += 256) {
      int r = l / 16, c = l % 16;
      int gcol = bn + r;
      float v = 0.f;
      if (gcol < 1200)      v = wf[(size_t)gcol * 400 + k0 + c];
      else if (gcol < 2400) v = wb[(size_t)(gcol - 1200) * 400 + k0 + c];
      Bs[c][r] = v;
    }
    __syncthreads();
    #pragma unroll
    for (int kk = 0; kk < 16; ++kk) {
      float a[4], b[4];
      #pragma unroll
      for (int u = 0; u < 4; ++u) { a[u] = As[kk][tr + u]; b[u] = Bs[kk][tc + u]; }
      #pragma unroll
      for (int u = 0; u < 4; ++u)
        #pragma unroll
        for (int v = 0; v < 4; ++v) acc[u][v] += a[u] * b[v];
    }
    __syncthreads();
  }
  for (int u = 0; u < 4; ++u) {
    int r = bm + tr + u;
    for (int v = 0; v < 4; ++v) {
      int c = bn + tc + v; if (c >= 2400) continue;
      float bias = (c < 1200) ? bf[c] : bb[c - 1200];
      C[(size_t)r * 2400 + c] = acc[u][v] + bias;
    }
  }
}

// ---------------------------------------------------------------------------
// 32x32-tile GEMM: C = A@B^T + bias (optional tanh) — r12-proven template
// ---------------------------------------------------------------------------
template<int TAG>
__global__ __launch_bounds__(256, 4)
void gemm32(const float* __restrict__ A, int lda,
            const float* __restrict__ Bw, int ldb,
            const float* __restrict__ bias,
            float* __restrict__ C, int ldc,
            int M, int N, int K, int act)
{
  __shared__ float As[32][33];
  __shared__ float Bs[32][33];
  const int bm = blockIdx.y * 32, bn = blockIdx.x * 32;
  const int tid = threadIdx.x;
  const int tr = (tid >> 4) * 2, tc = (tid & 15) * 2;
  float acc[2][2] = {};
  for (int k0 = 0; k0 < K; k0 += 32) {
    #pragma unroll
    for (int p = 0; p < 4; ++p) {
      int l = tid + p * 256;
      int r = l >> 5, c = l & 31;
      As[c][r] = (bm + r < M) ? A[(size_t)(bm + r) * lda + k0 + c] : 0.f;
      Bs[c][r] = (bn + r < N) ? Bw[(size_t)(bn + r) * ldb + k0 + c] : 0.f;
    }
    __syncthreads();
    #pragma unroll
    for (int kk = 0; kk < 32; ++kk) {
      float a0 = As[kk][tr], a1 = As[kk][tr + 1];
      float b0 = Bs[kk][tc], b1 = Bs[kk][tc + 1];
      acc[0][0] += a0 * b0; acc[0][1] += a0 * b1;
      acc[1][0] += a1 * b0; acc[1][1] += a1 * b1;
    }
    __syncthreads();
  }
  #pragma unroll
  for (int u = 0; u < 2; ++u) {
    int r = bm + tr + u; if (r >= M) continue;
    #pragma unroll
    for (int v = 0; v < 2; ++v) {
      int c = bn + tc + v; if (c >= N) continue;
      float xv = acc[u][v] + (bias ? bias[c] : 0.f);
      if (act == 1) xv = tanhf(xv);
      C[(size_t)r * ldc + c] = xv;
    }
  }
}

// ---------------------------------------------------------------------------
// gemm_rp: merged R + pre1 (both consume enc, K=800). grid (17,16):
//  x<13  -> R   = tanh(enc @ W_r^T + b_r)    [512][400]
//  x>=13 -> pre1 = enc @ W_d1[:, :800]^T+b_d1 [512][100]
// Body is the proven gemm32 inner loop.
// ---------------------------------------------------------------------------
__global__ __launch_bounds__(256, 4)
void gemm_rp(const float* __restrict__ enc,
             const float* __restrict__ W_r,  const float* __restrict__ b_r,
             const float* __restrict__ W_d1, const float* __restrict__ b_d1,
             float* __restrict__ Rbuf, float* __restrict__ pre1)
{
  const bool isR = (blockIdx.x < 13);
  const float* Bw  = isR ? W_r : W_d1;
  const float* bias = isR ? b_r : b_d1;
  float* C   = isR ? Rbuf : pre1;
  const int ldb = isR ? 800 : 1600;
  const int ldc = isR ? 400 : 100;
  const int N   = isR ? 400 : 100;
  const int act = isR ? 1 : 0;
  const int bn  = (isR ? blockIdx.x : (blockIdx.x - 13)) * 32;
  const int bm  = blockIdx.y * 32;
  const int tid = threadIdx.x;
  const int tr = (tid >> 4) * 2, tc = (tid & 15) * 2;
  __shared__ float As[32][33];
  __shared__ float Bs[32][33];
  float acc[2][2] = {};
  for (int k0 = 0; k0 < 800; k0 += 32) {
    #pragma unroll
    for (int p = 0; p < 4; ++p) {
      int l = tid + p * 256;
      int r = l >> 5, c = l & 31;
      As[c][r] = enc[(size_t)(bm + r) * 800 + k0 + c];
      Bs[c][r] = (bn + r < N) ? Bw[(size_t)(bn + r) * ldb + k0 + c] : 0.f;
    }
    __syncthreads();
    #pragma unroll
    for (int kk = 0; kk < 32; ++kk) {
      float a0 = As[kk][tr], a1 = As[kk][tr + 1];
      float b0 = Bs[kk][tc], b1 = Bs[kk][tc + 1];
      acc[0][0] += a0 * b0; acc[0][1] += a0 * b1;
      acc[1][0] += a1 * b0; acc[1][1] += a1 * b1;
    }
    __syncthreads();
  }
  #pragma unroll
  for (int u = 0; u < 2; ++u) {
    int r = bm + tr + u;
    #pragma unroll
    for (int v = 0; v < 2; ++v) {
      int c = bn + tc + v; if (c >= N) continue;
      float xv = acc[u][v] + bias[c];
      if (act == 1) xv = tanhf(xv);
      C[(size_t)r * ldc + c] = xv;
    }
  }
}

// ---------------------------------------------------------------------------
// K3: bidirectional GRU scan — EXACT r12 kernel (role-split, 1040-1065us floor)
// ---------------------------------------------------------------------------
#define GRU_NB 25
#define GRU_CHUNK 16
#define LDA64(p) __hip_atomic_load((p), __ATOMIC_RELAXED, __HIP_MEMORY_SCOPE_AGENT)
__global__ __launch_bounds__(256, 1)
void gru_scan_kernel(const float* __restrict__ gi,
                     const float* __restrict__ whh_f, const float* __restrict__ bhh_f,
                     const float* __restrict__ whh_b, const float* __restrict__ bhh_b,
                     float* __restrict__ enc,
                     float* __restrict__ mean,
                     unsigned long long* __restrict__ hbuf)
{
  const int tid = threadIdx.x;
  const int dir = blockIdx.x / GRU_NB;
  const int b   = blockIdx.x % GRU_NB;
  const float* whh = dir ? whh_b : whh_f;
  const float* bhh = dir ? bhh_b : bhh_f;
  unsigned long long* hb = hbuf + (size_t)dir * 800;
  const int i0 = b * GRU_CHUNK;

  __shared__ float wl[48][400];
  __shared__ float hs[400];
  __shared__ float ghs[48];

  for (int l = tid; l < 48 * 400; l += 256) {
    int lr = l / 400, c = l % 400;
    int g = lr / GRU_CHUNK, ii = lr % GRU_CHUNK;
    wl[lr][c] = whh[(size_t)(g * 400 + i0 + ii) * 400 + c];
  }

  const int i  = tid >> 4;
  const int cc = tid & 15;
  const int c0 = cc * 25;

  float blr = 0.f, blz = 0.f, bln = 0.f, msum = 0.f;
  float g0r = 0.f, g0z = 0.f, g0n = 0.f;
  float g1r = 0.f, g1z = 0.f, g1n = 0.f;
  if (tid < GRU_CHUNK) {
    blr = bhh[i0 + tid];
    blz = bhh[400 + i0 + tid];
    bln = bhh[800 + i0 + tid];
    {
      int t0 = dir ? 511 : 0;
      const float* g = gi + (size_t)t0 * 2400 + dir * 1200 + i0 + tid;
      g0r = g[0]; g0z = g[400]; g0n = g[800];
      int t1 = dir ? 510 : 1;
      g = gi + (size_t)t1 * 2400 + dir * 1200 + i0 + tid;
      g1r = g[0]; g1z = g[400]; g1n = g[800];
    }
  }
  __syncthreads();

  const int p = tid - 64;
  const bool h2 = (p >= 0) && (p < 16);

  for (int t = 0; t < 512; ++t) {
    const int t_in = dir ? (511 - t) : t;
    if (tid >= 64) {
      const unsigned long long* src = hb + (t & 1) * 400;
      const unsigned want = (unsigned)t;
      unsigned long long a0, a1, a2 = 0, b0, b1, b2 = 0, r0, r1, r2 = 0;
      a0 = LDA64(src + p); a1 = LDA64(src + p + 192); if (h2) a2 = LDA64(src + p + 384);
      b0 = LDA64(src + p); b1 = LDA64(src + p + 192); if (h2) b2 = LDA64(src + p + 384);
      for (;;) {
        bool ok = ((unsigned)(a0 >> 32) == want) && ((unsigned)(a1 >> 32) == want)
                  && (!h2 || ((unsigned)(a2 >> 32) == want));
        if (__all(ok)) { r0 = a0; r1 = a1; r2 = a2; break; }
        a0 = LDA64(src + p); a1 = LDA64(src + p + 192); if (h2) a2 = LDA64(src + p + 384);
        ok = ((unsigned)(b0 >> 32) == want) && ((unsigned)(b1 >> 32) == want)
             && (!h2 || ((unsigned)(b2 >> 32) == want));
        if (__all(ok)) { r0 = b0; r1 = b1; r2 = b2; break; }
        b0 = LDA64(src + p); b1 = LDA64(src + p + 192); if (h2) b2 = LDA64(src + p + 384);
      }
      hs[p] = __uint_as_float((unsigned)r0);
      hs[p + 192] = __uint_as_float((unsigned)r1);
      if (h2) hs[p + 384] = __uint_as_float((unsigned)r2);
    }
    __syncthreads();   // [1] hs ready

    float a0 = 0.f, a1 = 0.f, a2 = 0.f;
    #pragma unroll
    for (int j = 0; j < 25; ++j) {
      float hv = hs[c0 + j];
      a0 += wl[i][c0 + j] * hv;
      a1 += wl[16 + i][c0 + j] * hv;
      a2 += wl[32 + i][c0 + j] * hv;
    }
    #pragma unroll
    for (int m = 1; m <= 8; m <<= 1) {
      a0 += __shfl_xor(a0, m);
      a1 += __shfl_xor(a1, m);
      a2 += __shfl_xor(a2, m);
    }
    if (cc == 0) { ghs[i] = a0; ghs[16 + i] = a1; ghs[32 + i] = a2; }
    __syncthreads();   // [2] ghs ready

    if (tid < GRU_CHUNK) {
      float r = 1.f / (1.f + expf(-(g0r + ghs[tid] + blr)));
      float z = 1.f / (1.f + expf(-(g0z + ghs[16 + tid] + blz)));
      float n = tanhf(g0n + r * (ghs[32 + tid] + bln));
      float hprev = hs[i0 + tid];
      float hn = (1.f - z) * n + z * hprev;
      msum += hn;
      unsigned long long pk =
          ((unsigned long long)(unsigned)(t + 1) << 32) |
          (unsigned long long)__float_as_uint(hn);
      __hip_atomic_store(hb + ((t + 1) & 1) * 400 + i0 + tid, pk,
                         __ATOMIC_RELAXED, __HIP_MEMORY_SCOPE_AGENT);
      enc[(size_t)t_in * 800 + dir * 400 + i0 + tid] = hn;
      g0r = g1r; g0z = g1z; g0n = g1n;
      int t2 = t + 2; if (t2 > 511) t2 = 511;
      int tn2 = dir ? (511 - t2) : t2;
      const float* g = gi + (size_t)tn2 * 2400 + dir * 1200 + i0 + tid;
      g1r = g[0]; g1z = g[400]; g1n = g[800];
    }
  }
  if (tid < GRU_CHUNK)
    mean[dir * 400 + i0 + tid] = msum * (1.f / 512.f);
}

// ---------------------------------------------------------------------------
// K6: decoder with doc + dt prologue. Parallel segment passes. (r12-proven)
// ---------------------------------------------------------------------------
__global__ __launch_bounds__(1024, 1)
void decoder_kernel(const float* __restrict__ pre1,
                    const float* __restrict__ Qb,
                    const float* __restrict__ mean,
                    const float* __restrict__ W_doc,
                    const float* __restrict__ b_doc,
                    const float* __restrict__ W_d1,
                    const float* __restrict__ W_d2,
                    const float* __restrict__ b_d2,
                    const int* __restrict__ nos_p,
                    float* __restrict__ out)
{
  const int tid = threadIdx.x;
  const int row = tid >> 1;
  const int half = tid & 1;
  __shared__ float mean_s[800];
  __shared__ float doc_s[400];
  __shared__ float dt_s[100];
  __shared__ float q[100];
  __shared__ float w2s[100];
  __shared__ int   selfl[512];
  __shared__ int   firstpos;
  __shared__ float red[16];

  if (tid < 800) mean_s[tid] = mean[tid];
  if (tid < 100) { q[tid] = 0.f; w2s[tid] = W_d2[tid]; }
  if (tid < 512) selfl[tid] = 0;
  __syncthreads();

  const int w = tid >> 6, l = tid & 63;
  for (int rr = 0; rr < 25; ++rr) {
    int r = w * 25 + rr;
    float s = 0.f;
    for (int k = l; k < 800; k += 64) s += W_doc[(size_t)r * 800 + k] * mean_s[k];
    s += __shfl_xor(s, 1);  s += __shfl_xor(s, 2);  s += __shfl_xor(s, 4);
    s += __shfl_xor(s, 8);  s += __shfl_xor(s, 16); s += __shfl_xor(s, 32);
    if (l == 0) doc_s[r] = tanhf(s + b_doc[r]);
  }
  __syncthreads();
  for (int r = w; r < 100; r += 16) {
    float s = 0.f;
    for (int k = l; k < 400; k += 64) s += W_d1[(size_t)r * 1600 + 1200 + k] * doc_s[k];
    s += __shfl_xor(s, 1);  s += __shfl_xor(s, 2);  s += __shfl_xor(s, 4);
    s += __shfl_xor(s, 8);  s += __shfl_xor(s, 16); s += __shfl_xor(s, 32);
    if (l == 0) dt_s[r] = s;
  }
  __syncthreads();

  float pr[50];
  #pragma unroll
  for (int k = 0; k < 50; ++k)
    pr[k] = pre1[(size_t)row * 100 + half * 50 + k] + dt_s[half * 50 + k];
  const float bd2 = b_d2[0];
  const int nos = nos_p[0];
  int count = 0, seg = 0;
  float logp_part = 0.f;
  __syncthreads();

  for (int pass = 0; pass < 600 && seg < 512; ++pass) {
    const bool allowed = (nos <= 0) || (count < nos);
    if (tid == 0) firstpos = 512;
    float acc = 0.f;
    #pragma unroll
    for (int k = 0; k < 50; ++k)
      acc += w2s[half * 50 + k] * tanhf(pr[k] + q[half * 50 + k]);
    acc += __shfl_xor(acc, 1);
    const float sv = acc + bd2;
    __syncthreads();
    if (allowed && half == 0 && row >= seg && sv > 0.f)
      atomicMin(&firstpos, row);
    __syncthreads();
    const int fp = allowed ? firstpos : 512;
    const int lim = (fp < 512) ? fp : 511;
    if (half == 0 && row >= seg && row <= lim) {
      float p = 1.f / (1.f + expf(-sv));
      float term = (row == fp) ? p : (1.f - p);
      logp_part += logf(term * 0.99999f + 5e-6f);
      if (row == fp) selfl[row] = 1;
    }
    if (fp < 512) {
      if (tid < 100) q[tid] += Qb[(size_t)fp * 100 + tid];
      count += 1;
      seg = fp + 1;
    } else {
      seg = 512;
    }
    __syncthreads();
  }

  float v = logp_part;
  v += __shfl_xor(v, 1);  v += __shfl_xor(v, 2);  v += __shfl_xor(v, 4);
  v += __shfl_xor(v, 8);  v += __shfl_xor(v, 16); v += __shfl_xor(v, 32);
  if ((tid & 63) == 0) red[tid >> 6] = v;
  __syncthreads();
  if (tid == 0) {
    float s = 0.f;
    #pragma unroll
    for (int ww = 0; ww < 16; ++ww) s += red[ww];
    out[0] = s;
  }
  if (half == 0) out[1 + row] = (float)selfl[row];
}

// ---------------------------------------------------------------------------
// Launcher. Fast path (ws >= 12.1 MB): 7 dispatches (r12 + 2 merges).
// ---------------------------------------------------------------------------
extern "C" void kernel_launch(void* const* d_in, const int* in_sizes, int n_in,
                              void* d_out, int out_size, void* d_ws, size_t ws_size,
                              hipStream_t stream) {
  const int*   x      = (const int*)  d_in[0];
  const int*   nos    = (const int*)  d_in[1];
  const float* emb    = (const float*)d_in[2];
  const float* cw[8];
  for (int k = 0; k < 8; ++k) cw[k] = (const float*)d_in[3 + k];
  const float* conv_b = (const float*)d_in[11];
  const float* w_ih_f = (const float*)d_in[12];
  const float* w_hh_f = (const float*)d_in[13];
  const float* b_ih_f = (const float*)d_in[14];
  const float* b_hh_f = (const float*)d_in[15];
  const float* w_ih_b = (const float*)d_in[16];
  const float* w_hh_b = (const float*)d_in[17];
  const float* b_ih_b = (const float*)d_in[18];
  const float* b_hh_b = (const float*)d_in[19];
  const float* W_doc  = (const float*)d_in[20];
  const float* b_doc  = (const float*)d_in[21];
  const float* W_d1   = (const float*)d_in[22];
  const float* b_d1   = (const float*)d_in[23];
  const float* W_d2   = (const float*)d_in[24];
  const float* b_d2   = (const float*)d_in[25];
  const float* W_r    = (const float*)d_in[26];
  const float* b_r    = (const float*)d_in[27];

  float* ws = (float*)d_ws;
  const size_t NEED_FAST = (size_t)3009664 * 4;   // bytes

  if (ws_size >= NEED_FAST) {
    float* Awin   = ws;                      // [512][3072]
    float* Wpad   = ws + 1572864;            // [400][3072] -> enc later
    float* pooled = ws + 2801664;            // [512][400]  -> pre1 later
    float* gi     = ws;                      // (Awin dead)
    unsigned long long* hbuf = (unsigned long long*)(ws + 3006464);  // 1600 u64
    float* enc    = ws + 1572864;            // (Wpad dead)
    float* mean   = ws + 1982464;            // 800
    float* Rbuf   = ws;                      // (gi dead after GRU)
    float* Qbuf   = ws + 204800;
    float* pre1   = ws + 2801664;            // (pooled dead after gemm_gi)

    // K1: window (blocks 0..511) + pad (blocks 512..911) in one launch
    window_pad_kernel<<<912, 256, 0, stream>>>(x, emb, Awin, 3072,
                                               cw[0], cw[1], cw[2], cw[3],
                                               cw[4], cw[5], cw[6], cw[7], Wpad);
    // pooled = Awin @ Wpad^T + conv_b  (208-block 32x32 tile — r12-proven)
    gemm32<0><<<dim3(13, 16), 256, 0, stream>>>(Awin, 3072, Wpad, 3072, conv_b,
                                                pooled, 400, 512, 400, 3072, 0);
    gemm_gi<<<dim3(38, 8), 256, 0, stream>>>(pooled, w_ih_f, b_ih_f, w_ih_b, b_ih_b,
                                             gi, hbuf);
    gru_scan_kernel<<<2 * GRU_NB, 256, 0, stream>>>(gi, w_hh_f, b_hh_f, w_hh_b, b_hh_b,
                                                    enc, mean, hbuf);
    // R + pre1 merged (both consume enc, K=800)
    gemm_rp<<<dim3(17, 16), 256, 0, stream>>>(enc, W_r, b_r, W_d1, b_d1, Rbuf, pre1);
    // Q = R @ W_d1[:,800:1200]^T
    gemm32<2><<<dim3(4, 16), 256, 0, stream>>>(Rbuf, 400, W_d1 + 800, 1600, nullptr,
                                               Qbuf, 100, 512, 100, 400, 0);
    decoder_kernel<<<1, 1024, 0, stream>>>(pre1, Qbuf, mean, W_doc, b_doc, W_d1,
                                           W_d2, b_d2, nos, (float*)d_out);
  } else {
    // fallback: r10/r12 layout + on-the-fly gemm_pool
    float* Awin   = ws;
    float* gi     = ws;
    float* Rbuf   = ws;
    float* Qbuf   = ws + 204800;
    unsigned long long* hbuf = (unsigned long long*)(ws + 1228800);
    float* pooled = ws + 1536000;
    float* pre1   = ws + 1536000;
    float* mean   = ws + 1587200;
    float* enc    = ws + 1740800;

    window_pad_kernel<<<512, 256, 0, stream>>>(x, emb, Awin, 3000,
                                               cw[0], cw[1], cw[2], cw[3],
                                               cw[4], cw[5], cw[6], cw[7], nullptr);
    gemm_pool<<<dim3(7, 8), 256, 0, stream>>>(Awin, cw[0], cw[1], cw[2], cw[3],
                                              cw[4], cw[5], cw[6], cw[7],
                                              conv_b, pooled);
    gemm_gi<<<dim3(38, 8), 256, 0, stream>>>(pooled, w_ih_f, b_ih_f, w_ih_b, b_ih_b,
                                             gi, hbuf);
    gru_scan_kernel<<<2 * GRU_NB, 256, 0, stream>>>(gi, w_hh_f, b_hh_f, w_hh_b, b_hh_b,
                                                    enc, mean, hbuf);
    gemm_rp<<<dim3(17, 16), 256, 0, stream>>>(enc, W_r, b_r, W_d1, b_d1, Rbuf, pre1);
    gemm32<2><<<dim3(4, 16), 256, 0, stream>>>(Rbuf, 400, W_d1 + 800, 1600, nullptr,
                                               Qbuf, 100, 512, 100, 400, 0);
    decoder_kernel<<<1, 1024, 0, stream>>>(pre1, Qbuf, mean, W_doc, b_doc, W_d1,
                                           W_d2, b_d2, nos, (float*)d_out);
  }
}

// Round 16
// 1681.167 us; speedup vs baseline: 1.2364x; 1.0366x over previous
//
#include <hip/hip_runtime.h>
#include <math.h>

// Problem dims
#define S_N   512
#define WL_N  100
#define E_N   200
#define OC_N  50
#define H_N   400

// ---------------------------------------------------------------------------
// K1: window_pad_kernel — blocks <512: Awin[s][dd*200+e] (r12 window body);
// blocks >=512: Wpad[gcol][3072] materialization (r12 pad body).
// ---------------------------------------------------------------------------
__global__ __launch_bounds__(256, 1)
void window_pad_kernel(const int* __restrict__ x, const float* __restrict__ emb,
                       float* __restrict__ Awin, int stride,
                       const float* __restrict__ cw0, const float* __restrict__ cw1,
                       const float* __restrict__ cw2, const float* __restrict__ cw3,
                       const float* __restrict__ cw4, const float* __restrict__ cw5,
                       const float* __restrict__ cw6, const float* __restrict__ cw7,
                       float* __restrict__ Wpad)
{
  const int tid = threadIdx.x;
  if (blockIdx.x >= 512) {
    const int gcol = blockIdx.x - 512;
    const float* cwA[8] = {cw0, cw1, cw2, cw3, cw4, cw5, cw6, cw7};
    const int K = gcol / 50, oc = gcol % 50;
    const int width = 2 * K + 1;
    const int lo = 7 - K;
    const float* base = cwA[K] + (size_t)oc * 200 * width;
    for (int k = tid; k < 3072; k += 256) {
      float v = 0.f;
      if (k < 3000) {
        int dd = k / 200, e = k - dd * 200;
        int off = dd - lo;
        if (off >= 0 && off < width) v = base[e * width + off];
      }
      Wpad[(size_t)gcol * 3072 + k] = v;
    }
    return;
  }
  const int s = blockIdx.x;
  __shared__ int xr[WL_N];
  __shared__ int Lsh;
  __shared__ float Apart[E_N][17];
  __shared__ float Bpart[E_N][9];
  if (tid < WL_N) xr[tid] = x[s * WL_N + tid];
  for (int idx = tid; idx < stride - 3000; idx += 256)
    Awin[(size_t)s * stride + 3000 + idx] = 0.f;
  __syncthreads();
  if (tid == 0) {
    int L = 0;
    for (int t = 0; t < WL_N; ++t) L += (xr[t] != 0) ? 1 : 0;
    Lsh = L;
  }
  __syncthreads();
  const int L = Lsh;  // in [20,100]
  const int Lp7 = (L + 7 < WL_N) ? (L + 7) : WL_N;
  if (tid < E_N) {
    const int e = tid;
    float acc = 0.f;
    for (int t = 0; t < Lp7; ++t) {
      acc += emb[(size_t)xr[t] * E_N + e];
      int m = t + 1;
      if (m <= 7) Bpart[e][m] = acc;
      int rel = m - (L - 7);
      if (rel >= 0 && rel < 15) Apart[e][rel] = acc;
    }
    const float accF = acc;
    const float invL = 1.f / (float)L;
    #pragma unroll
    for (int dd = 0; dd < 15; ++dd) {
      int m = L - 7 + dd;
      float A = (m > WL_N) ? accF : Apart[e][dd];
      int d = dd - 7;
      float B = (d > 0) ? Bpart[e][d] : 0.f;
      Awin[(size_t)s * stride + dd * 200 + e] = (A - B) * invL;
    }
  }
}

// ---------------------------------------------------------------------------
// K1b-fallback: gemm_pool on-the-fly (r10-proven; used only if ws too small)
// ---------------------------------------------------------------------------
__global__ __launch_bounds__(256, 2)
void gemm_pool(const float* __restrict__ Awin,
               const float* __restrict__ cw0, const float* __restrict__ cw1,
               const float* __restrict__ cw2, const float* __restrict__ cw3,
               const float* __restrict__ cw4, const float* __restrict__ cw5,
               const float* __restrict__ cw6, const float* __restrict__ cw7,
               const float* __restrict__ conv_b,
               float* __restrict__ pooled)
{
  __shared__ float As[16][65];
  __shared__ float Bs[16][65];
  const int bm = blockIdx.y * 64, bn = blockIdx.x * 64;
  const int tid = threadIdx.x;
  const int tr = (tid / 16) * 4, tc = (tid % 16) * 4;
  const int c = tid & 15;

  const float* cwA[8] = {cw0, cw1, cw2, cw3, cw4, cw5, cw6, cw7};
  const float* base_i[4];
  int lo_i[4], w_i[4];
  bool valid_i[4];
  #pragma unroll
  for (int i = 0; i < 4; ++i) {
    int gcol = bn + (tid >> 4) + 16 * i;
    bool v = (gcol < 400);
    int g = v ? gcol : 0;
    int K = g / 50, oc = g % 50;
    int width = 2 * K + 1;
    valid_i[i] = v;
    lo_i[i] = 7 - K;
    w_i[i] = width;
    base_i[i] = cwA[K] + (size_t)oc * 200 * width;
  }

  float acc[4][4] = {};
  int e = c, dd = 0;
  for (int k0 = 0; k0 < 3000; k0 += 16) {
    for (int l = tid; l < 64 * 16; l += 256) {
      int r = l >> 4, cc2 = l & 15;
      int k = k0 + cc2;
      As[cc2][r] = (k < 3000) ? Awin[(size_t)(bm + r) * 3000 + k] : 0.f;
    }
    #pragma unroll
    for (int i = 0; i < 4; ++i) {
      int r = (tid >> 4) + 16 * i;
      int off = dd - lo_i[i];
      float v = 0.f;
      if (valid_i[i] && off >= 0 && off < w_i[i])
        v = base_i[i][e * w_i[i] + off];
      Bs[c][r] = v;
    }
    __syncthreads();
    #pragma unroll
    for (int kk = 0; kk < 16; ++kk) {
      float a[4], b[4];
      #pragma unroll
      for (int u = 0; u < 4; ++u) { a[u] = As[kk][tr + u]; b[u] = Bs[kk][tc + u]; }
      #pragma unroll
      for (int u = 0; u < 4; ++u)
        #pragma unroll
        for (int v = 0; v < 4; ++v) acc[u][v] += a[u] * b[v];
    }
    __syncthreads();
    e += 16;
    if (e >= 200) { e -= 200; dd += 1; }
  }
  for (int u = 0; u < 4; ++u) {
    int r = bm + tr + u;
    for (int v = 0; v < 4; ++v) {
      int cc2 = bn + tc + v; if (cc2 >= 400) continue;
      pooled[(size_t)r * 400 + cc2] = acc[u][v] + conv_b[cc2];
    }
  }
}

// ---------------------------------------------------------------------------
// K2: gemm_gi (+ zero hbuf in block (0,0)) — r12-proven
// ---------------------------------------------------------------------------
__global__ __launch_bounds__(256, 2)
void gemm_gi(const float* __restrict__ A,
             const float* __restrict__ wf, const float* __restrict__ bf,
             const float* __restrict__ wb, const float* __restrict__ bb,
             float* __restrict__ C,
             unsigned long long* __restrict__ hz)
{
  __shared__ float As[16][65];
  __shared__ float Bs[16][65];
  const int bm = blockIdx.y * 64, bn = blockIdx.x * 64;
  const int tid = threadIdx.x;
  const int tr = (tid / 16) * 4, tc = (tid % 16) * 4;
  if (blockIdx.x == 0 && blockIdx.y == 0)
    for (int l = tid; l < 1600; l += 256) hz[l] = 0ull;
  float acc[4][4] = {};
  for (int k0 = 0; k0 < 400; k0 += 16) {
    for (int l = tid; l < 64 * 16; l += 256) {
      int r = l / 16, c = l % 16;
      As[c][r] = A[(size_t)(bm + r) * 400 + k0 + c];
    }
    for (int l = tid; l < 64 * 16; l += 256) {
      int r = l / 16, c = l % 16;
      int gcol = bn + r;
      float v = 0.f;
      if (gcol < 1200)      v = wf[(size_t)gcol * 400 + k0 + c];
      else if (gcol < 2400) v = wb[(size_t)(gcol - 1200) * 400 + k0 + c];
      Bs[c][r] = v;
    }
    __syncthreads();
    #pragma unroll
    for (int kk = 0; kk < 16; ++kk) {
      float a[4], b[4];
      #pragma unroll
      for (int u = 0; u < 4; ++u) { a[u] = As[kk][tr + u]; b[u] = Bs[kk][tc + u]; }
      #pragma unroll
      for (int u = 0; u < 4; ++u)
        #pragma unroll
        for (int v = 0; v < 4; ++v) acc[u][v] += a[u] * b[v];
    }
    __syncthreads();
  }
  for (int u = 0; u < 4; ++u) {
    int r = bm + tr + u;
    for (int v = 0; v < 4; ++v) {
      int c = bn + tc + v; if (c >= 2400) continue;
      float bias = (c < 1200) ? bf[c] : bb[c - 1200];
      C[(size_t)r * 2400 + c] = acc[u][v] + bias;
    }
  }
}

// ---------------------------------------------------------------------------
// 32x32-tile GEMM: C = A@B^T + bias (optional tanh) — r12-proven template
// ---------------------------------------------------------------------------
template<int TAG>
__global__ __launch_bounds__(256, 4)
void gemm32(const float* __restrict__ A, int lda,
            const float* __restrict__ Bw, int ldb,
            const float* __restrict__ bias,
            float* __restrict__ C, int ldc,
            int M, int N, int K, int act)
{
  __shared__ float As[32][33];
  __shared__ float Bs[32][33];
  const int bm = blockIdx.y * 32, bn = blockIdx.x * 32;
  const int tid = threadIdx.x;
  const int tr = (tid >> 4) * 2, tc = (tid & 15) * 2;
  float acc[2][2] = {};
  for (int k0 = 0; k0 < K; k0 += 32) {
    #pragma unroll
    for (int p = 0; p < 4; ++p) {
      int l = tid + p * 256;
      int r = l >> 5, c = l & 31;
      As[c][r] = (bm + r < M) ? A[(size_t)(bm + r) * lda + k0 + c] : 0.f;
      Bs[c][r] = (bn + r < N) ? Bw[(size_t)(bn + r) * ldb + k0 + c] : 0.f;
    }
    __syncthreads();
    #pragma unroll
    for (int kk = 0; kk < 32; ++kk) {
      float a0 = As[kk][tr], a1 = As[kk][tr + 1];
      float b0 = Bs[kk][tc], b1 = Bs[kk][tc + 1];
      acc[0][0] += a0 * b0; acc[0][1] += a0 * b1;
      acc[1][0] += a1 * b0; acc[1][1] += a1 * b1;
    }
    __syncthreads();
  }
  #pragma unroll
  for (int u = 0; u < 2; ++u) {
    int r = bm + tr + u; if (r >= M) continue;
    #pragma unroll
    for (int v = 0; v < 2; ++v) {
      int c = bn + tc + v; if (c >= N) continue;
      float xv = acc[u][v] + (bias ? bias[c] : 0.f);
      if (act == 1) xv = tanhf(xv);
      C[(size_t)r * ldc + c] = xv;
    }
  }
}

// ---------------------------------------------------------------------------
// gemm_rp: merged R + pre1 (both consume enc, K=800). r15-proven.
// ---------------------------------------------------------------------------
__global__ __launch_bounds__(256, 4)
void gemm_rp(const float* __restrict__ enc,
             const float* __restrict__ W_r,  const float* __restrict__ b_r,
             const float* __restrict__ W_d1, const float* __restrict__ b_d1,
             float* __restrict__ Rbuf, float* __restrict__ pre1)
{
  const bool isR = (blockIdx.x < 13);
  const float* Bw  = isR ? W_r : W_d1;
  const float* bias = isR ? b_r : b_d1;
  float* C   = isR ? Rbuf : pre1;
  const int ldb = isR ? 800 : 1600;
  const int ldc = isR ? 400 : 100;
  const int N   = isR ? 400 : 100;
  const int act = isR ? 1 : 0;
  const int bn  = (isR ? blockIdx.x : (blockIdx.x - 13)) * 32;
  const int bm  = blockIdx.y * 32;
  const int tid = threadIdx.x;
  const int tr = (tid >> 4) * 2, tc = (tid & 15) * 2;
  __shared__ float As[32][33];
  __shared__ float Bs[32][33];
  float acc[2][2] = {};
  for (int k0 = 0; k0 < 800; k0 += 32) {
    #pragma unroll
    for (int p = 0; p < 4; ++p) {
      int l = tid + p * 256;
      int r = l >> 5, c = l & 31;
      As[c][r] = enc[(size_t)(bm + r) * 800 + k0 + c];
      Bs[c][r] = (bn + r < N) ? Bw[(size_t)(bn + r) * ldb + k0 + c] : 0.f;
    }
    __syncthreads();
    #pragma unroll
    for (int kk = 0; kk < 32; ++kk) {
      float a0 = As[kk][tr], a1 = As[kk][tr + 1];
      float b0 = Bs[kk][tc], b1 = Bs[kk][tc + 1];
      acc[0][0] += a0 * b0; acc[0][1] += a0 * b1;
      acc[1][0] += a1 * b0; acc[1][1] += a1 * b1;
    }
    __syncthreads();
  }
  #pragma unroll
  for (int u = 0; u < 2; ++u) {
    int r = bm + tr + u;
    #pragma unroll
    for (int v = 0; v < 2; ++v) {
      int c = bn + tc + v; if (c >= N) continue;
      float xv = acc[u][v] + bias[c];
      if (act == 1) xv = tanhf(xv);
      C[(size_t)r * ldc + c] = xv;
    }
  }
}

// ---------------------------------------------------------------------------
// K3: bidirectional GRU scan — EXACT r12 kernel (role-split, 1040-1065us floor)
// ---------------------------------------------------------------------------
#define GRU_NB 25
#define GRU_CHUNK 16
#define LDA64(p) __hip_atomic_load((p), __ATOMIC_RELAXED, __HIP_MEMORY_SCOPE_AGENT)
__global__ __launch_bounds__(256, 1)
void gru_scan_kernel(const float* __restrict__ gi,
                     const float* __restrict__ whh_f, const float* __restrict__ bhh_f,
                     const float* __restrict__ whh_b, const float* __restrict__ bhh_b,
                     float* __restrict__ enc,
                     float* __restrict__ mean,
                     unsigned long long* __restrict__ hbuf)
{
  const int tid = threadIdx.x;
  const int dir = blockIdx.x / GRU_NB;
  const int b   = blockIdx.x % GRU_NB;
  const float* whh = dir ? whh_b : whh_f;
  const float* bhh = dir ? bhh_b : bhh_f;
  unsigned long long* hb = hbuf + (size_t)dir * 800;
  const int i0 = b * GRU_CHUNK;

  __shared__ float wl[48][400];
  __shared__ float hs[400];
  __shared__ float ghs[48];

  for (int l = tid; l < 48 * 400; l += 256) {
    int lr = l / 400, c = l % 400;
    int g = lr / GRU_CHUNK, ii = lr % GRU_CHUNK;
    wl[lr][c] = whh[(size_t)(g * 400 + i0 + ii) * 400 + c];
  }

  const int i  = tid >> 4;
  const int cc = tid & 15;
  const int c0 = cc * 25;

  float blr = 0.f, blz = 0.f, bln = 0.f, msum = 0.f;
  float g0r = 0.f, g0z = 0.f, g0n = 0.f;
  float g1r = 0.f, g1z = 0.f, g1n = 0.f;
  if (tid < GRU_CHUNK) {
    blr = bhh[i0 + tid];
    blz = bhh[400 + i0 + tid];
    bln = bhh[800 + i0 + tid];
    {
      int t0 = dir ? 511 : 0;
      const float* g = gi + (size_t)t0 * 2400 + dir * 1200 + i0 + tid;
      g0r = g[0]; g0z = g[400]; g0n = g[800];
      int t1 = dir ? 510 : 1;
      g = gi + (size_t)t1 * 2400 + dir * 1200 + i0 + tid;
      g1r = g[0]; g1z = g[400]; g1n = g[800];
    }
  }
  __syncthreads();

  const int p = tid - 64;
  const bool h2 = (p >= 0) && (p < 16);

  for (int t = 0; t < 512; ++t) {
    const int t_in = dir ? (511 - t) : t;
    if (tid >= 64) {
      const unsigned long long* src = hb + (t & 1) * 400;
      const unsigned want = (unsigned)t;
      unsigned long long a0, a1, a2 = 0, b0, b1, b2 = 0, r0, r1, r2 = 0;
      a0 = LDA64(src + p); a1 = LDA64(src + p + 192); if (h2) a2 = LDA64(src + p + 384);
      b0 = LDA64(src + p); b1 = LDA64(src + p + 192); if (h2) b2 = LDA64(src + p + 384);
      for (;;) {
        bool ok = ((unsigned)(a0 >> 32) == want) && ((unsigned)(a1 >> 32) == want)
                  && (!h2 || ((unsigned)(a2 >> 32) == want));
        if (__all(ok)) { r0 = a0; r1 = a1; r2 = a2; break; }
        a0 = LDA64(src + p); a1 = LDA64(src + p + 192); if (h2) a2 = LDA64(src + p + 384);
        ok = ((unsigned)(b0 >> 32) == want) && ((unsigned)(b1 >> 32) == want)
             && (!h2 || ((unsigned)(b2 >> 32) == want));
        if (__all(ok)) { r0 = b0; r1 = b1; r2 = b2; break; }
        b0 = LDA64(src + p); b1 = LDA64(src + p + 192); if (h2) b2 = LDA64(src + p + 384);
      }
      hs[p] = __uint_as_float((unsigned)r0);
      hs[p + 192] = __uint_as_float((unsigned)r1);
      if (h2) hs[p + 384] = __uint_as_float((unsigned)r2);
    }
    __syncthreads();   // [1] hs ready

    float a0 = 0.f, a1 = 0.f, a2 = 0.f;
    #pragma unroll
    for (int j = 0; j < 25; ++j) {
      float hv = hs[c0 + j];
      a0 += wl[i][c0 + j] * hv;
      a1 += wl[16 + i][c0 + j] * hv;
      a2 += wl[32 + i][c0 + j] * hv;
    }
    #pragma unroll
    for (int m = 1; m <= 8; m <<= 1) {
      a0 += __shfl_xor(a0, m);
      a1 += __shfl_xor(a1, m);
      a2 += __shfl_xor(a2, m);
    }
    if (cc == 0) { ghs[i] = a0; ghs[16 + i] = a1; ghs[32 + i] = a2; }
    __syncthreads();   // [2] ghs ready

    if (tid < GRU_CHUNK) {
      float r = 1.f / (1.f + expf(-(g0r + ghs[tid] + blr)));
      float z = 1.f / (1.f + expf(-(g0z + ghs[16 + tid] + blz)));
      float n = tanhf(g0n + r * (ghs[32 + tid] + bln));
      float hprev = hs[i0 + tid];
      float hn = (1.f - z) * n + z * hprev;
      msum += hn;
      unsigned long long pk =
          ((unsigned long long)(unsigned)(t + 1) << 32) |
          (unsigned long long)__float_as_uint(hn);
      __hip_atomic_store(hb + ((t + 1) & 1) * 400 + i0 + tid, pk,
                         __ATOMIC_RELAXED, __HIP_MEMORY_SCOPE_AGENT);
      enc[(size_t)t_in * 800 + dir * 400 + i0 + tid] = hn;
      g0r = g1r; g0z = g1z; g0n = g1n;
      int t2 = t + 2; if (t2 > 511) t2 = 511;
      int tn2 = dir ? (511 - t2) : t2;
      const float* g = gi + (size_t)tn2 * 2400 + dir * 1200 + i0 + tid;
      g1r = g[0]; g1z = g[400]; g1n = g[800];
    }
  }
  if (tid < GRU_CHUNK)
    mean[dir * 400 + i0 + tid] = msum * (1.f / 512.f);
}

// ---------------------------------------------------------------------------
// K6: decoder with doc + dt prologue; Q computed ON DEMAND from Rbuf for the
// (<=num_of_sent) selected rows — replaces the dedicated Q GEMM dispatch.
// q[m] += sum_k Rbuf[fp][k] * W_d1[m][800+k]; 800 threads, 8 lanes/m.
// ---------------------------------------------------------------------------
__global__ __launch_bounds__(1024, 1)
void decoder_kernel(const float* __restrict__ pre1,
                    const float* __restrict__ Rbuf,   // [512][400]
                    const float* __restrict__ mean,
                    const float* __restrict__ W_doc,
                    const float* __restrict__ b_doc,
                    const float* __restrict__ W_d1,
                    const float* __restrict__ W_d2,
                    const float* __restrict__ b_d2,
                    const int* __restrict__ nos_p,
                    float* __restrict__ out)
{
  const int tid = threadIdx.x;
  const int row = tid >> 1;
  const int half = tid & 1;
  __shared__ float mean_s[800];
  __shared__ float doc_s[400];
  __shared__ float dt_s[100];
  __shared__ float q[100];
  __shared__ float w2s[100];
  __shared__ int   selfl[512];
  __shared__ int   firstpos;
  __shared__ float red[16];

  if (tid < 800) mean_s[tid] = mean[tid];
  if (tid < 100) { q[tid] = 0.f; w2s[tid] = W_d2[tid]; }
  if (tid < 512) selfl[tid] = 0;
  __syncthreads();

  const int w = tid >> 6, l = tid & 63;
  for (int rr = 0; rr < 25; ++rr) {
    int r = w * 25 + rr;
    float s = 0.f;
    for (int k = l; k < 800; k += 64) s += W_doc[(size_t)r * 800 + k] * mean_s[k];
    s += __shfl_xor(s, 1);  s += __shfl_xor(s, 2);  s += __shfl_xor(s, 4);
    s += __shfl_xor(s, 8);  s += __shfl_xor(s, 16); s += __shfl_xor(s, 32);
    if (l == 0) doc_s[r] = tanhf(s + b_doc[r]);
  }
  __syncthreads();
  for (int r = w; r < 100; r += 16) {
    float s = 0.f;
    for (int k = l; k < 400; k += 64) s += W_d1[(size_t)r * 1600 + 1200 + k] * doc_s[k];
    s += __shfl_xor(s, 1);  s += __shfl_xor(s, 2);  s += __shfl_xor(s, 4);
    s += __shfl_xor(s, 8);  s += __shfl_xor(s, 16); s += __shfl_xor(s, 32);
    if (l == 0) dt_s[r] = s;
  }
  __syncthreads();

  float pr[50];
  #pragma unroll
  for (int k = 0; k < 50; ++k)
    pr[k] = pre1[(size_t)row * 100 + half * 50 + k] + dt_s[half * 50 + k];
  const float bd2 = b_d2[0];
  const int nos = nos_p[0];
  int count = 0, seg = 0;
  float logp_part = 0.f;
  __syncthreads();

  for (int pass = 0; pass < 600 && seg < 512; ++pass) {
    const bool allowed = (nos <= 0) || (count < nos);
    if (tid == 0) firstpos = 512;
    float acc = 0.f;
    #pragma unroll
    for (int k = 0; k < 50; ++k)
      acc += w2s[half * 50 + k] * tanhf(pr[k] + q[half * 50 + k]);
    acc += __shfl_xor(acc, 1);
    const float sv = acc + bd2;
    __syncthreads();
    if (allowed && half == 0 && row >= seg && sv > 0.f)
      atomicMin(&firstpos, row);
    __syncthreads();
    const int fp = allowed ? firstpos : 512;
    const int lim = (fp < 512) ? fp : 511;
    if (half == 0 && row >= seg && row <= lim) {
      float p = 1.f / (1.f + expf(-sv));
      float term = (row == fp) ? p : (1.f - p);
      logp_part += logf(term * 0.99999f + 5e-6f);
      if (row == fp) selfl[row] = 1;
    }
    if (fp < 512) {
      // on-demand q update: q[m] += W_d1[m][800:1200] . Rbuf[fp]
      if (tid < 800) {
        const int m = tid >> 3, kc = tid & 7;
        const float* rrow = Rbuf + (size_t)fp * 400 + kc * 50;
        const float* wrow = W_d1 + (size_t)m * 1600 + 800 + kc * 50;
        float s = 0.f;
        #pragma unroll 10
        for (int k = 0; k < 50; ++k) s += wrow[k] * rrow[k];
        s += __shfl_xor(s, 1);  s += __shfl_xor(s, 2);  s += __shfl_xor(s, 4);
        if (kc == 0) q[m] += s;
      }
      count += 1;
      seg = fp + 1;
    } else {
      seg = 512;
    }
    __syncthreads();
  }

  float v = logp_part;
  v += __shfl_xor(v, 1);  v += __shfl_xor(v, 2);  v += __shfl_xor(v, 4);
  v += __shfl_xor(v, 8);  v += __shfl_xor(v, 16); v += __shfl_xor(v, 32);
  if ((tid & 63) == 0) red[tid >> 6] = v;
  __syncthreads();
  if (tid == 0) {
    float s = 0.f;
    #pragma unroll
    for (int ww = 0; ww < 16; ++ww) s += red[ww];
    out[0] = s;
  }
  if (half == 0) out[1 + row] = (float)selfl[row];
}

// ---------------------------------------------------------------------------
// Launcher. Fast path (ws >= 12.1 MB): 6 dispatches.
// ---------------------------------------------------------------------------
extern "C" void kernel_launch(void* const* d_in, const int* in_sizes, int n_in,
                              void* d_out, int out_size, void* d_ws, size_t ws_size,
                              hipStream_t stream) {
  const int*   x      = (const int*)  d_in[0];
  const int*   nos    = (const int*)  d_in[1];
  const float* emb    = (const float*)d_in[2];
  const float* cw[8];
  for (int k = 0; k < 8; ++k) cw[k] = (const float*)d_in[3 + k];
  const float* conv_b = (const float*)d_in[11];
  const float* w_ih_f = (const float*)d_in[12];
  const float* w_hh_f = (const float*)d_in[13];
  const float* b_ih_f = (const float*)d_in[14];
  const float* b_hh_f = (const float*)d_in[15];
  const float* w_ih_b = (const float*)d_in[16];
  const float* w_hh_b = (const float*)d_in[17];
  const float* b_ih_b = (const float*)d_in[18];
  const float* b_hh_b = (const float*)d_in[19];
  const float* W_doc  = (const float*)d_in[20];
  const float* b_doc  = (const float*)d_in[21];
  const float* W_d1   = (const float*)d_in[22];
  const float* b_d1   = (const float*)d_in[23];
  const float* W_d2   = (const float*)d_in[24];
  const float* b_d2   = (const float*)d_in[25];
  const float* W_r    = (const float*)d_in[26];
  const float* b_r    = (const float*)d_in[27];

  float* ws = (float*)d_ws;
  const size_t NEED_FAST = (size_t)3009664 * 4;   // bytes

  if (ws_size >= NEED_FAST) {
    float* Awin   = ws;                      // [512][3072]
    float* Wpad   = ws + 1572864;            // [400][3072] -> enc later
    float* pooled = ws + 2801664;            // [512][400]  -> pre1 later
    float* gi     = ws;                      // (Awin dead)
    unsigned long long* hbuf = (unsigned long long*)(ws + 3006464);  // 1600 u64
    float* enc    = ws + 1572864;            // (Wpad dead)
    float* mean   = ws + 1982464;            // 800
    float* Rbuf   = ws;                      // (gi dead after GRU)
    float* pre1   = ws + 2801664;            // (pooled dead after gemm_gi)

    window_pad_kernel<<<912, 256, 0, stream>>>(x, emb, Awin, 3072,
                                               cw[0], cw[1], cw[2], cw[3],
                                               cw[4], cw[5], cw[6], cw[7], Wpad);
    gemm32<0><<<dim3(13, 16), 256, 0, stream>>>(Awin, 3072, Wpad, 3072, conv_b,
                                                pooled, 400, 512, 400, 3072, 0);
    gemm_gi<<<dim3(38, 8), 256, 0, stream>>>(pooled, w_ih_f, b_ih_f, w_ih_b, b_ih_b,
                                             gi, hbuf);
    gru_scan_kernel<<<2 * GRU_NB, 256, 0, stream>>>(gi, w_hh_f, b_hh_f, w_hh_b, b_hh_b,
                                                    enc, mean, hbuf);
    gemm_rp<<<dim3(17, 16), 256, 0, stream>>>(enc, W_r, b_r, W_d1, b_d1, Rbuf, pre1);
    decoder_kernel<<<1, 1024, 0, stream>>>(pre1, Rbuf, mean, W_doc, b_doc, W_d1,
                                           W_d2, b_d2, nos, (float*)d_out);
  } else {
    // fallback: r10/r12 layout + on-the-fly gemm_pool
    float* Awin   = ws;
    float* gi     = ws;
    float* Rbuf   = ws;
    unsigned long long* hbuf = (unsigned long long*)(ws + 1228800);
    float* pooled = ws + 1536000;
    float* pre1   = ws + 1536000;
    float* mean   = ws + 1587200;
    float* enc    = ws + 1740800;

    window_pad_kernel<<<512, 256, 0, stream>>>(x, emb, Awin, 3000,
                                               cw[0], cw[1], cw[2], cw[3],
                                               cw[4], cw[5], cw[6], cw[7], nullptr);
    gemm_pool<<<dim3(7, 8), 256, 0, stream>>>(Awin, cw[0], cw[1], cw[2], cw[3],
                                              cw[4], cw[5], cw[6], cw[7],
                                              conv_b, pooled);
    gemm_gi<<<dim3(38, 8), 256, 0, stream>>>(pooled, w_ih_f, b_ih_f, w_ih_b, b_ih_b,
                                             gi, hbuf);
    gru_scan_kernel<<<2 * GRU_NB, 256, 0, stream>>>(gi, w_hh_f, b_hh_f, w_hh_b, b_hh_b,
                                                    enc, mean, hbuf);
    gemm_rp<<<dim3(17, 16), 256, 0, stream>>>(enc, W_r, b_r, W_d1, b_d1, Rbuf, pre1);
    decoder_kernel<<<1, 1024, 0, stream>>>(pre1, Rbuf, mean, W_doc, b_doc, W_d1,
                                           W_d2, b_d2, nos, (float*)d_out);
  }
}